// Round 1
// baseline (4470.148 us; speedup 1.0000x reference)
//
#include <hip/hip_runtime.h>
#include <math.h>

#define BATCH   4
#define NSEQ    2048
#define DIM     1024
#define HEADS   16
#define DHEAD   64
#define INNER   1024
#define MTOT    (BATCH*NSEQ)     // 8192
#define SCALE   0.03125f         // 1024^-0.5

// ---------------------------------------------------------------------------
// Generic 64x64-tile fp32 GEMM pieces (BM=BN=64, BK=16, 256 thr, 4x4/thread)
// ---------------------------------------------------------------------------

// QKV projection: X[8192][1024] @ W[1024][3072] -> scatter to q/k/v [b,h,n,d]
__global__ __launch_bounds__(256) void gemm_qkv(const float* __restrict__ X,
                                                const float* __restrict__ W,
                                                float* __restrict__ qb,
                                                float* __restrict__ kb,
                                                float* __restrict__ vb)
{
    __shared__ float As[64][17];   // [row][k]
    __shared__ float Bs[16][65];   // [k][col]

    const int bn = blockIdx.x;           // 0..47
    const int bm = blockIdx.y;           // 0..127
    const int t  = threadIdx.x;
    const int tx = t & 15, ty = t >> 4;

    const int row0 = bm * 64;
    const int col0 = bn * 64;

    const int arow = t >> 2, aseg = t & 3;      // A tile load mapping
    const int brow = t >> 4, bseg = t & 15;     // B tile load mapping

    float acc[4][4];
#pragma unroll
    for (int i = 0; i < 4; ++i)
#pragma unroll
        for (int j = 0; j < 4; ++j) acc[i][j] = 0.f;

    for (int k0 = 0; k0 < DIM; k0 += 16) {
        __syncthreads();
        // load A tile 64x16
        {
            float4 v = *reinterpret_cast<const float4*>(&X[(size_t)(row0 + arow) * DIM + k0 + aseg * 4]);
            As[arow][aseg * 4 + 0] = v.x;
            As[arow][aseg * 4 + 1] = v.y;
            As[arow][aseg * 4 + 2] = v.z;
            As[arow][aseg * 4 + 3] = v.w;
        }
        // load B tile 16x64
        {
            float4 v = *reinterpret_cast<const float4*>(&W[(size_t)(k0 + brow) * (3 * INNER) + col0 + bseg * 4]);
            Bs[brow][bseg * 4 + 0] = v.x;
            Bs[brow][bseg * 4 + 1] = v.y;
            Bs[brow][bseg * 4 + 2] = v.z;
            Bs[brow][bseg * 4 + 3] = v.w;
        }
        __syncthreads();
#pragma unroll
        for (int kk = 0; kk < 16; ++kk) {
            float a[4], b[4];
#pragma unroll
            for (int i = 0; i < 4; ++i) a[i] = As[ty * 4 + i][kk];
#pragma unroll
            for (int j = 0; j < 4; ++j) b[j] = Bs[kk][tx * 4 + j];
#pragma unroll
            for (int i = 0; i < 4; ++i)
#pragma unroll
                for (int j = 0; j < 4; ++j) acc[i][j] = fmaf(a[i], b[j], acc[i][j]);
        }
    }

    // scatter into q/k/v [b][h][n][d]
#pragma unroll
    for (int i = 0; i < 4; ++i) {
        const int row = row0 + ty * 4 + i;
        const int bb = row >> 11, nn = row & 2047;
#pragma unroll
        for (int j = 0; j < 4; ++j) {
            const int col   = col0 + tx * 4 + j;      // 0..3071
            const int part  = col >> 10;
            const int inner = col & 1023;
            const int h = inner >> 6, d = inner & 63;
            float* dst = (part == 0) ? qb : (part == 1) ? kb : vb;
            dst[(((size_t)bb * HEADS + h) * NSEQ + nn) * DHEAD + d] = acc[i][j];
        }
    }
}

// Output projection: A[8192][1024] @ W[1024][1024] + bias -> out
__global__ __launch_bounds__(256) void gemm_out(const float* __restrict__ A,
                                                const float* __restrict__ W,
                                                const float* __restrict__ bias,
                                                float* __restrict__ out)
{
    __shared__ float As[64][17];
    __shared__ float Bs[16][65];

    const int bn = blockIdx.x;           // 0..15
    const int bm = blockIdx.y;           // 0..127
    const int t  = threadIdx.x;
    const int tx = t & 15, ty = t >> 4;

    const int row0 = bm * 64;
    const int col0 = bn * 64;

    const int arow = t >> 2, aseg = t & 3;
    const int brow = t >> 4, bseg = t & 15;

    float acc[4][4];
#pragma unroll
    for (int i = 0; i < 4; ++i)
#pragma unroll
        for (int j = 0; j < 4; ++j) acc[i][j] = 0.f;

    for (int k0 = 0; k0 < INNER; k0 += 16) {
        __syncthreads();
        {
            float4 v = *reinterpret_cast<const float4*>(&A[(size_t)(row0 + arow) * INNER + k0 + aseg * 4]);
            As[arow][aseg * 4 + 0] = v.x;
            As[arow][aseg * 4 + 1] = v.y;
            As[arow][aseg * 4 + 2] = v.z;
            As[arow][aseg * 4 + 3] = v.w;
        }
        {
            float4 v = *reinterpret_cast<const float4*>(&W[(size_t)(k0 + brow) * DIM + col0 + bseg * 4]);
            Bs[brow][bseg * 4 + 0] = v.x;
            Bs[brow][bseg * 4 + 1] = v.y;
            Bs[brow][bseg * 4 + 2] = v.z;
            Bs[brow][bseg * 4 + 3] = v.w;
        }
        __syncthreads();
#pragma unroll
        for (int kk = 0; kk < 16; ++kk) {
            float a[4], b[4];
#pragma unroll
            for (int i = 0; i < 4; ++i) a[i] = As[ty * 4 + i][kk];
#pragma unroll
            for (int j = 0; j < 4; ++j) b[j] = Bs[kk][tx * 4 + j];
#pragma unroll
            for (int i = 0; i < 4; ++i)
#pragma unroll
                for (int j = 0; j < 4; ++j) acc[i][j] = fmaf(a[i], b[j], acc[i][j]);
        }
    }

#pragma unroll
    for (int i = 0; i < 4; ++i) {
        const int row = row0 + ty * 4 + i;
#pragma unroll
        for (int j = 0; j < 4; ++j) {
            const int col = col0 + tx * 4 + j;
            out[(size_t)row * DIM + col] = acc[i][j] + bias[col];
        }
    }
}

// ---------------------------------------------------------------------------
// Flash-style fp32 attention. Grid: (b*h, n/64). 256 threads.
// Each thread: row r = t/4 of the 64-row Q tile, quarter qd = t%4
// (owns 16 S-columns and 16 O-dims). P tile reuses the K LDS buffer.
// ---------------------------------------------------------------------------
__global__ __launch_bounds__(256) void attn_fp32(const float* __restrict__ qb,
                                                 const float* __restrict__ kb,
                                                 const float* __restrict__ vb,
                                                 float* __restrict__ ob)
{
    __shared__ float Qs[64][65];
    __shared__ float KPs[64][65];   // K tile, then reused for P tile
    __shared__ float Vs[64][65];

    const int bh   = blockIdx.x;    // 0..63
    const int qblk = blockIdx.y;    // 0..31
    const int t    = threadIdx.x;
    const int r    = t >> 2;        // 0..63 query row within tile
    const int qd   = t & 3;         // quarter

    const size_t base = (size_t)bh * NSEQ * DHEAD;

    // load Q tile (64x64)
    {
        const float4* src = reinterpret_cast<const float4*>(qb + base + (size_t)(qblk * 64 + r) * DHEAD);
#pragma unroll
        for (int jj = 0; jj < 4; ++jj) {
            float4 v = src[qd * 4 + jj];
            Qs[r][qd * 16 + jj * 4 + 0] = v.x;
            Qs[r][qd * 16 + jj * 4 + 1] = v.y;
            Qs[r][qd * 16 + jj * 4 + 2] = v.z;
            Qs[r][qd * 16 + jj * 4 + 3] = v.w;
        }
    }

    float o[16];
#pragma unroll
    for (int i = 0; i < 16; ++i) o[i] = 0.f;
    float m_r = -INFINITY, l_r = 0.f;

    for (int kb_i = 0; kb_i < NSEQ / 64; ++kb_i) {
        __syncthreads();   // previous iteration's P/V reads done
        // load K and V tiles (64x64 each)
        {
            const float4* ksrc = reinterpret_cast<const float4*>(kb + base + (size_t)(kb_i * 64 + r) * DHEAD);
            const float4* vsrc = reinterpret_cast<const float4*>(vb + base + (size_t)(kb_i * 64 + r) * DHEAD);
#pragma unroll
            for (int jj = 0; jj < 4; ++jj) {
                float4 kv = ksrc[qd * 4 + jj];
                KPs[r][qd * 16 + jj * 4 + 0] = kv.x;
                KPs[r][qd * 16 + jj * 4 + 1] = kv.y;
                KPs[r][qd * 16 + jj * 4 + 2] = kv.z;
                KPs[r][qd * 16 + jj * 4 + 3] = kv.w;
                float4 vv = vsrc[qd * 4 + jj];
                Vs[r][qd * 16 + jj * 4 + 0] = vv.x;
                Vs[r][qd * 16 + jj * 4 + 1] = vv.y;
                Vs[r][qd * 16 + jj * 4 + 2] = vv.z;
                Vs[r][qd * 16 + jj * 4 + 3] = vv.w;
            }
        }
        __syncthreads();

        // S = Q K^T * scale for this thread's 16 columns
        float s[16];
#pragma unroll
        for (int c = 0; c < 16; ++c) s[c] = 0.f;
        for (int d = 0; d < DHEAD; ++d) {
            const float qv = Qs[r][d];
#pragma unroll
            for (int c = 0; c < 16; ++c)
                s[c] = fmaf(qv, KPs[qd * 16 + c][d], s[c]);
        }
#pragma unroll
        for (int c = 0; c < 16; ++c) s[c] *= SCALE;

        // online softmax
        float mloc = s[0];
#pragma unroll
        for (int c = 1; c < 16; ++c) mloc = fmaxf(mloc, s[c]);
        mloc = fmaxf(mloc, __shfl_xor(mloc, 1));
        mloc = fmaxf(mloc, __shfl_xor(mloc, 2));
        const float m_new = fmaxf(m_r, mloc);
        const float alpha = __expf(m_r - m_new);
        float p[16];
        float lloc = 0.f;
#pragma unroll
        for (int c = 0; c < 16; ++c) {
            p[c] = __expf(s[c] - m_new);
            lloc += p[c];
        }
        lloc += __shfl_xor(lloc, 1);
        lloc += __shfl_xor(lloc, 2);
        l_r = l_r * alpha + lloc;
        m_r = m_new;
#pragma unroll
        for (int i = 0; i < 16; ++i) o[i] *= alpha;

        __syncthreads();   // everyone done reading K tile
        // write P into the K buffer
#pragma unroll
        for (int c = 0; c < 16; ++c) KPs[r][qd * 16 + c] = p[c];
        __syncthreads();   // P visible

        // O += P V  (this thread's 16 dims)
        for (int c = 0; c < 64; ++c) {
            const float pv = KPs[r][c];
#pragma unroll
            for (int dd = 0; dd < 16; ++dd)
                o[dd] = fmaf(pv, Vs[c][qd * 16 + dd], o[dd]);
        }
    }

    // epilogue: normalize and write to [b][n][h*64+d]
    const float inv = 1.0f / l_r;
    const int bb = bh >> 4, h = bh & 15;
    const int n = qblk * 64 + r;
    float* dst = ob + ((size_t)bb * NSEQ + n) * INNER + h * 64 + qd * 16;
#pragma unroll
    for (int dd = 0; dd < 16; ++dd) dst[dd] = o[dd] * inv;
}

// ---------------------------------------------------------------------------

extern "C" void kernel_launch(void* const* d_in, const int* in_sizes, int n_in,
                              void* d_out, int out_size, void* d_ws, size_t ws_size,
                              hipStream_t stream) {
    const float* x     = (const float*)d_in[0];   // [4,2048,1024]
    const float* w_qkv = (const float*)d_in[1];   // [1024,3072]
    const float* w_out = (const float*)d_in[2];   // [1024,1024]
    const float* b_out = (const float*)d_in[3];   // [1024]
    float* out = (float*)d_out;                   // [4,2048,1024]

    float* ws = (float*)d_ws;
    const size_t per = (size_t)BATCH * HEADS * NSEQ * DHEAD;  // 8,388,608 floats
    float* qb = ws;
    float* kbuf = qb + per;
    float* vbuf = kbuf + per;
    float* obuf = vbuf + per;                     // [b][n][inner]

    dim3 blk(256);
    gemm_qkv<<<dim3(3 * INNER / 64, MTOT / 64), blk, 0, stream>>>(x, w_qkv, qb, kbuf, vbuf);
    attn_fp32<<<dim3(BATCH * HEADS, NSEQ / 64), blk, 0, stream>>>(qb, kbuf, vbuf, obuf);
    gemm_out<<<dim3(DIM / 64, MTOT / 64), blk, 0, stream>>>(obuf, w_out, b_out, out);
}

// Round 2
// 288.251 us; speedup vs baseline: 15.5078x; 15.5078x over previous
//
#include <hip/hip_runtime.h>
#include <math.h>

#define BATCH   4
#define NSEQ    2048
#define DIM     1024
#define HEADS   16
#define DHEAD   64
#define INNER   1024
#define MTOT    (BATCH*NSEQ)     // 8192
// softmax computed in log2 domain: s * SCALE * log2(e)
#define SC_L2E  0.04508422f      // (1024^-0.5) * 1.4426950408889634

typedef __attribute__((ext_vector_type(8))) unsigned short u16x8;
typedef __attribute__((ext_vector_type(4))) unsigned short u16x4;
typedef __attribute__((ext_vector_type(8))) short          bf16x8;
typedef __attribute__((ext_vector_type(4))) float          f32x4;

__device__ __forceinline__ unsigned short f2bf(float f) {
    unsigned int u = __builtin_bit_cast(unsigned int, f);
    u += 0x7FFFu + ((u >> 16) & 1u);       // RNE
    return (unsigned short)(u >> 16);
}

// ---------------------------------------------------------------------------
// fp32 -> bf16 elementwise convert (x)
// ---------------------------------------------------------------------------
__global__ __launch_bounds__(256) void cvt_bf16(const float* __restrict__ in,
                                                unsigned short* __restrict__ out)
{
    const int i = blockIdx.x * 256 + threadIdx.x;   // one u16x8 per thread
    const float4* p = reinterpret_cast<const float4*>(in) + (size_t)i * 2;
    float4 a = p[0], b = p[1];
    u16x8 o;
    o[0]=f2bf(a.x); o[1]=f2bf(a.y); o[2]=f2bf(a.z); o[3]=f2bf(a.w);
    o[4]=f2bf(b.x); o[5]=f2bf(b.y); o[6]=f2bf(b.z); o[7]=f2bf(b.w);
    reinterpret_cast<u16x8*>(out)[i] = o;
}

// ---------------------------------------------------------------------------
// fp32 [R][C] -> bf16 [C][R] transpose (weights)
// ---------------------------------------------------------------------------
__global__ __launch_bounds__(256) void transp_bf16(const float* __restrict__ in,
                                                   unsigned short* __restrict__ out,
                                                   int R, int C)
{
    __shared__ float tile[32][33];
    const int c0 = blockIdx.x * 32, r0 = blockIdx.y * 32;
    const int tx = threadIdx.x & 31, ty = threadIdx.x >> 5;   // ty 0..7
#pragma unroll
    for (int i = 0; i < 32; i += 8)
        tile[ty + i][tx] = in[(size_t)(r0 + ty + i) * C + c0 + tx];
    __syncthreads();
#pragma unroll
    for (int i = 0; i < 32; i += 8)
        out[(size_t)(c0 + ty + i) * R + r0 + tx] = f2bf(tile[tx][ty + i]);
}

// ---------------------------------------------------------------------------
// bf16 MFMA GEMM, 128x128 tile, BK=32, 4 waves (2x2), 16 mfma/wave/iter.
// A [M][1024] row-major bf16, Bt [N][1024] row-major bf16 (= B^T).
// ---------------------------------------------------------------------------

// QKV: M=8192, N=3072. Scatter epilogue -> q[b,h,n,d], k[b,h,n,d], vt[b,h,d,n]
__global__ __launch_bounds__(256) void gemm_qkv_mfma(const unsigned short* __restrict__ A,
                                                     const unsigned short* __restrict__ Bt,
                                                     unsigned short* __restrict__ qb,
                                                     unsigned short* __restrict__ kb,
                                                     unsigned short* __restrict__ vt)
{
    __shared__ unsigned short As[128][40];
    __shared__ unsigned short Bs[128][40];

    const int t = threadIdx.x;
    const int l = t & 63, w = t >> 6;
    const int wr = w >> 1, wc = w & 1;
    const int g = l >> 4, ql = l & 15;
    const int row0 = blockIdx.y * 128;
    const int col0 = blockIdx.x * 128;

    const int srow = t >> 1;            // staging row 0..127
    const int shalf = t & 1;            // k-half (16 elems)

    f32x4 acc[4][4];
#pragma unroll
    for (int mi = 0; mi < 4; ++mi)
#pragma unroll
        for (int ni = 0; ni < 4; ++ni)
#pragma unroll
            for (int r = 0; r < 4; ++r) acc[mi][ni][r] = 0.f;

    for (int k0 = 0; k0 < DIM; k0 += 32) {
        __syncthreads();
        {
            const unsigned short* ag = A  + (size_t)(row0 + srow) * DIM + k0 + shalf * 16;
            const unsigned short* bg = Bt + (size_t)(col0 + srow) * DIM + k0 + shalf * 16;
            u16x8 a0 = *reinterpret_cast<const u16x8*>(ag);
            u16x8 a1 = *reinterpret_cast<const u16x8*>(ag + 8);
            u16x8 b0 = *reinterpret_cast<const u16x8*>(bg);
            u16x8 b1 = *reinterpret_cast<const u16x8*>(bg + 8);
            *reinterpret_cast<u16x8*>(&As[srow][shalf * 16])     = a0;
            *reinterpret_cast<u16x8*>(&As[srow][shalf * 16 + 8]) = a1;
            *reinterpret_cast<u16x8*>(&Bs[srow][shalf * 16])     = b0;
            *reinterpret_cast<u16x8*>(&Bs[srow][shalf * 16 + 8]) = b1;
        }
        __syncthreads();

        bf16x8 af[4], bf[4];
#pragma unroll
        for (int mi = 0; mi < 4; ++mi)
            af[mi] = *reinterpret_cast<const bf16x8*>(&As[wr * 64 + mi * 16 + ql][g * 8]);
#pragma unroll
        for (int ni = 0; ni < 4; ++ni)
            bf[ni] = *reinterpret_cast<const bf16x8*>(&Bs[wc * 64 + ni * 16 + ql][g * 8]);
#pragma unroll
        for (int mi = 0; mi < 4; ++mi)
#pragma unroll
            for (int ni = 0; ni < 4; ++ni)
                acc[mi][ni] = __builtin_amdgcn_mfma_f32_16x16x32_bf16(af[mi], bf[ni], acc[mi][ni], 0, 0, 0);
    }

    // epilogue: C row m -> (b,n); col c -> part(q/k/v), h, d
#pragma unroll
    for (int mi = 0; mi < 4; ++mi) {
        const int m0 = row0 + wr * 64 + mi * 16 + g * 4;   // rows m0..m0+3
        const int b  = m0 >> 11, n0 = m0 & 2047;
#pragma unroll
        for (int ni = 0; ni < 4; ++ni) {
            const int c = col0 + wc * 64 + ni * 16 + ql;
            const int part = c >> 10, inner = c & 1023;
            const int h = inner >> 6, d = inner & 63;
            if (part == 2) {
                u16x4 pk;
#pragma unroll
                for (int r = 0; r < 4; ++r) pk[r] = f2bf(acc[mi][ni][r]);
                *reinterpret_cast<u16x4*>(&vt[(((size_t)b * HEADS + h) * DHEAD + d) * NSEQ + n0]) = pk;
            } else {
                unsigned short* dst = (part == 0 ? qb : kb)
                                      + (((size_t)b * HEADS + h) * NSEQ + n0) * DHEAD + d;
#pragma unroll
                for (int r = 0; r < 4; ++r) dst[(size_t)r * DHEAD] = f2bf(acc[mi][ni][r]);
            }
        }
    }
}

// out-proj: M=8192, N=1024, + bias, fp32 out
__global__ __launch_bounds__(256) void gemm_out_mfma(const unsigned short* __restrict__ A,
                                                     const unsigned short* __restrict__ Bt,
                                                     const float* __restrict__ bias,
                                                     float* __restrict__ out)
{
    __shared__ unsigned short As[128][40];
    __shared__ unsigned short Bs[128][40];

    const int t = threadIdx.x;
    const int l = t & 63, w = t >> 6;
    const int wr = w >> 1, wc = w & 1;
    const int g = l >> 4, ql = l & 15;
    const int row0 = blockIdx.y * 128;
    const int col0 = blockIdx.x * 128;

    const int srow = t >> 1;
    const int shalf = t & 1;

    f32x4 acc[4][4];
#pragma unroll
    for (int mi = 0; mi < 4; ++mi)
#pragma unroll
        for (int ni = 0; ni < 4; ++ni)
#pragma unroll
            for (int r = 0; r < 4; ++r) acc[mi][ni][r] = 0.f;

    for (int k0 = 0; k0 < INNER; k0 += 32) {
        __syncthreads();
        {
            const unsigned short* ag = A  + (size_t)(row0 + srow) * INNER + k0 + shalf * 16;
            const unsigned short* bg = Bt + (size_t)(col0 + srow) * INNER + k0 + shalf * 16;
            u16x8 a0 = *reinterpret_cast<const u16x8*>(ag);
            u16x8 a1 = *reinterpret_cast<const u16x8*>(ag + 8);
            u16x8 b0 = *reinterpret_cast<const u16x8*>(bg);
            u16x8 b1 = *reinterpret_cast<const u16x8*>(bg + 8);
            *reinterpret_cast<u16x8*>(&As[srow][shalf * 16])     = a0;
            *reinterpret_cast<u16x8*>(&As[srow][shalf * 16 + 8]) = a1;
            *reinterpret_cast<u16x8*>(&Bs[srow][shalf * 16])     = b0;
            *reinterpret_cast<u16x8*>(&Bs[srow][shalf * 16 + 8]) = b1;
        }
        __syncthreads();

        bf16x8 af[4], bf[4];
#pragma unroll
        for (int mi = 0; mi < 4; ++mi)
            af[mi] = *reinterpret_cast<const bf16x8*>(&As[wr * 64 + mi * 16 + ql][g * 8]);
#pragma unroll
        for (int ni = 0; ni < 4; ++ni)
            bf[ni] = *reinterpret_cast<const bf16x8*>(&Bs[wc * 64 + ni * 16 + ql][g * 8]);
#pragma unroll
        for (int mi = 0; mi < 4; ++mi)
#pragma unroll
            for (int ni = 0; ni < 4; ++ni)
                acc[mi][ni] = __builtin_amdgcn_mfma_f32_16x16x32_bf16(af[mi], bf[ni], acc[mi][ni], 0, 0, 0);
    }

#pragma unroll
    for (int mi = 0; mi < 4; ++mi) {
        const int m0 = row0 + wr * 64 + mi * 16 + g * 4;
#pragma unroll
        for (int ni = 0; ni < 4; ++ni) {
            const int c = col0 + wc * 64 + ni * 16 + ql;
            const float bv = bias[c];
#pragma unroll
            for (int r = 0; r < 4; ++r)
                out[(size_t)(m0 + r) * DIM + c] = acc[mi][ni][r] + bv;
        }
    }
}

// ---------------------------------------------------------------------------
// MFMA flash attention, swapped operands: S^T = K·Q^T, O^T = V^T·P^T.
// Grid (b*h=64, n/64=32), 256 threads = 4 waves; wave w owns q-rows w*16..+16.
// Per-lane q-column association: q = w*16 + (lane&15) in BOTH S^T and O^T.
// ---------------------------------------------------------------------------
__global__ __launch_bounds__(256) void attn_mfma(const unsigned short* __restrict__ qg,
                                                 const unsigned short* __restrict__ kg,
                                                 const unsigned short* __restrict__ vtg,
                                                 unsigned short* __restrict__ og)
{
    __shared__ unsigned short Qs [64][72];
    __shared__ unsigned short Ks [64][72];
    __shared__ unsigned short Vts[64][72];   // [d][j]
    __shared__ unsigned short Ps [64][72];   // [q][j]

    const int bh = blockIdx.x;
    const int b = bh >> 4, h = bh & 15;
    const int qblk = blockIdx.y;
    const int t = threadIdx.x, l = t & 63, w = t >> 6;
    const int g = l >> 4, ql = l & 15;

    const size_t hb = (size_t)bh * NSEQ * DHEAD;

    // stage Q tile (64 rows x 64 d)
    {
        const int r = t >> 2, seg = t & 3;
        const u16x8* src = reinterpret_cast<const u16x8*>(qg + hb + (size_t)(qblk * 64 + r) * DHEAD + seg * 16);
        *reinterpret_cast<u16x8*>(&Qs[r][seg * 16])     = src[0];
        *reinterpret_cast<u16x8*>(&Qs[r][seg * 16 + 8]) = src[1];
    }
    __syncthreads();

    // Q fragments are loop-invariant: B-operand of S^T (col q=ql, d = g*8..)
    bf16x8 qf0 = *reinterpret_cast<const bf16x8*>(&Qs[w * 16 + ql][g * 8]);
    bf16x8 qf1 = *reinterpret_cast<const bf16x8*>(&Qs[w * 16 + ql][32 + g * 8]);

    f32x4 acc_o[4];
#pragma unroll
    for (int dt = 0; dt < 4; ++dt)
#pragma unroll
        for (int r = 0; r < 4; ++r) acc_o[dt][r] = 0.f;
    float m_r = -INFINITY, l_r = 0.f;

    for (int kbi = 0; kbi < NSEQ / 64; ++kbi) {
        __syncthreads();   // previous iteration's K/V reads done
        {
            const int r = t >> 2, seg = t & 3;
            const u16x8* ks = reinterpret_cast<const u16x8*>(kg  + hb + (size_t)(kbi * 64 + r) * DHEAD + seg * 16);
            *reinterpret_cast<u16x8*>(&Ks[r][seg * 16])     = ks[0];
            *reinterpret_cast<u16x8*>(&Ks[r][seg * 16 + 8]) = ks[1];
            const u16x8* vs = reinterpret_cast<const u16x8*>(vtg + hb + (size_t)r * NSEQ + kbi * 64 + seg * 16);
            *reinterpret_cast<u16x8*>(&Vts[r][seg * 16])     = vs[0];
            *reinterpret_cast<u16x8*>(&Vts[r][seg * 16 + 8]) = vs[1];
        }
        __syncthreads();

        // S^T[j][q] = K[j][:]·Q[q][:],  j = jt*16 + g*4 + reg, q = w*16 + ql
        f32x4 sacc[4];
#pragma unroll
        for (int jt = 0; jt < 4; ++jt)
#pragma unroll
            for (int r = 0; r < 4; ++r) sacc[jt][r] = 0.f;
#pragma unroll
        for (int jt = 0; jt < 4; ++jt) {
            bf16x8 kf0 = *reinterpret_cast<const bf16x8*>(&Ks[jt * 16 + ql][g * 8]);
            bf16x8 kf1 = *reinterpret_cast<const bf16x8*>(&Ks[jt * 16 + ql][32 + g * 8]);
            sacc[jt] = __builtin_amdgcn_mfma_f32_16x16x32_bf16(kf0, qf0, sacc[jt], 0, 0, 0);
            sacc[jt] = __builtin_amdgcn_mfma_f32_16x16x32_bf16(kf1, qf1, sacc[jt], 0, 0, 0);
        }

        // per-lane online softmax (one q-column per lane, 16 j-values local)
        float sv[16];
#pragma unroll
        for (int jt = 0; jt < 4; ++jt)
#pragma unroll
            for (int r = 0; r < 4; ++r) sv[jt * 4 + r] = sacc[jt][r] * SC_L2E;
        float mx = sv[0];
#pragma unroll
        for (int i = 1; i < 16; ++i) mx = fmaxf(mx, sv[i]);
        mx = fmaxf(mx, __shfl_xor(mx, 16));
        mx = fmaxf(mx, __shfl_xor(mx, 32));
        const float m_new = fmaxf(m_r, mx);
        const float alpha = exp2f(m_r - m_new);
        float p[16], ps = 0.f;
#pragma unroll
        for (int i = 0; i < 16; ++i) { p[i] = exp2f(sv[i] - m_new); ps += p[i]; }
        ps += __shfl_xor(ps, 16);
        ps += __shfl_xor(ps, 32);
        l_r = l_r * alpha + ps;
        m_r = m_new;
#pragma unroll
        for (int dt = 0; dt < 4; ++dt)
#pragma unroll
            for (int r = 0; r < 4; ++r) acc_o[dt][r] *= alpha;

        // write P^T -> Ps[q][j], 8B packed (j = jt*16 + g*4 + reg)
#pragma unroll
        for (int jt = 0; jt < 4; ++jt) {
            u16x4 pk;
#pragma unroll
            for (int r = 0; r < 4; ++r) pk[r] = f2bf(p[jt * 4 + r]);
            *reinterpret_cast<u16x4*>(&Ps[w * 16 + ql][jt * 16 + g * 4]) = pk;
        }

        // O^T[d][q] += Vt[d][:]·P^T[:][q]   (same-wave Ps rows, no barrier)
#pragma unroll
        for (int js = 0; js < 2; ++js) {
            bf16x8 pf = *reinterpret_cast<const bf16x8*>(&Ps[w * 16 + ql][js * 32 + g * 8]);
#pragma unroll
            for (int dt = 0; dt < 4; ++dt) {
                bf16x8 vf = *reinterpret_cast<const bf16x8*>(&Vts[dt * 16 + ql][js * 32 + g * 8]);
                acc_o[dt] = __builtin_amdgcn_mfma_f32_16x16x32_bf16(vf, pf, acc_o[dt], 0, 0, 0);
            }
        }
    }

    // epilogue: O[b][n][h*64 + d] bf16, d = dt*16 + g*4 + reg, n = qblk*64 + w*16 + ql
    const float rinv = 1.0f / l_r;
    const int n = qblk * 64 + w * 16 + ql;
    unsigned short* dst = og + ((size_t)b * NSEQ + n) * INNER + h * DHEAD;
#pragma unroll
    for (int dt = 0; dt < 4; ++dt) {
        u16x4 pk;
#pragma unroll
        for (int r = 0; r < 4; ++r) pk[r] = f2bf(acc_o[dt][r] * rinv);
        *reinterpret_cast<u16x4*>(&dst[dt * 16 + g * 4]) = pk;
    }
}

// ---------------------------------------------------------------------------

extern "C" void kernel_launch(void* const* d_in, const int* in_sizes, int n_in,
                              void* d_out, int out_size, void* d_ws, size_t ws_size,
                              hipStream_t stream) {
    const float* x     = (const float*)d_in[0];   // [4,2048,1024]
    const float* w_qkv = (const float*)d_in[1];   // [1024,3072]
    const float* w_out = (const float*)d_in[2];   // [1024,1024]
    const float* b_out = (const float*)d_in[3];   // [1024]
    float* out = (float*)d_out;                   // [4,2048,1024]

    unsigned short* ws = (unsigned short*)d_ws;
    const size_t nX  = (size_t)MTOT * DIM;            // 8,388,608
    const size_t nWq = (size_t)DIM * 3 * INNER;       // 3,145,728
    const size_t nWo = (size_t)DIM * INNER;           // 1,048,576
    unsigned short* Xb  = ws;
    unsigned short* Wqt = Xb  + nX;
    unsigned short* Wot = Wqt + nWq;
    unsigned short* qb  = Wot + nWo;
    unsigned short* kb  = qb  + nX;
    unsigned short* vt  = kb  + nX;
    unsigned short* Ob  = vt  + nX;

    cvt_bf16<<<dim3(nX / 8 / 256), dim3(256), 0, stream>>>(x, Xb);
    transp_bf16<<<dim3(3 * INNER / 32, DIM / 32), dim3(256), 0, stream>>>(w_qkv, Wqt, DIM, 3 * INNER);
    transp_bf16<<<dim3(DIM / 32, INNER / 32), dim3(256), 0, stream>>>(w_out, Wot, INNER, DIM);

    gemm_qkv_mfma<<<dim3(3 * INNER / 128, MTOT / 128), dim3(256), 0, stream>>>(Xb, Wqt, qb, kb, vt);
    attn_mfma<<<dim3(BATCH * HEADS, NSEQ / 64), dim3(256), 0, stream>>>(qb, kb, vt, Ob);
    gemm_out_mfma<<<dim3(DIM / 128, MTOT / 128), dim3(256), 0, stream>>>(Ob, Wot, b_out, out);
}

// Round 3
// 250.223 us; speedup vs baseline: 17.8647x; 1.1520x over previous
//
#include <hip/hip_runtime.h>
#include <math.h>

#define BATCH   4
#define NSEQ    2048
#define DIM     1024
#define HEADS   16
#define DHEAD   64
#define INNER   1024
#define MTOT    (BATCH*NSEQ)     // 8192
// softmax in log2 domain: SCALE * log2(e), folded into Q at QKV epilogue
#define SC_L2E  0.04508422f

typedef __attribute__((ext_vector_type(8))) unsigned short u16x8;
typedef __attribute__((ext_vector_type(4))) unsigned short u16x4;
typedef __attribute__((ext_vector_type(8))) short          bf16x8;
typedef __attribute__((ext_vector_type(4))) float          f32x4;

__device__ __forceinline__ unsigned short f2bf(float f) {
    unsigned int u = __builtin_bit_cast(unsigned int, f);
    u += 0x7FFFu + ((u >> 16) & 1u);       // RNE
    return (unsigned short)(u >> 16);
}

__device__ __forceinline__ float fexp2(float x) {
    float r; asm("v_exp_f32 %0, %1" : "=v"(r) : "v"(x)); return r;
}

__device__ __forceinline__ unsigned int cvtpk(float lo, float hi) {
    unsigned int r; asm("v_cvt_pk_bf16_f32 %0, %1, %2" : "=v"(r) : "v"(lo), "v"(hi));
    return r;
}

// async global->LDS, 16B per lane; lds base must be wave-uniform
#define GLDS16(gp, lp) __builtin_amdgcn_global_load_lds( \
    (const __attribute__((address_space(1))) unsigned int*)(gp), \
    (__attribute__((address_space(3))) unsigned int*)(lp), 16, 0, 0)

// ---------------------------------------------------------------------------
// fp32 -> bf16 elementwise convert (x)
// ---------------------------------------------------------------------------
__global__ __launch_bounds__(256) void cvt_bf16(const float* __restrict__ in,
                                                unsigned short* __restrict__ out)
{
    const int i = blockIdx.x * 256 + threadIdx.x;
    const float4* p = reinterpret_cast<const float4*>(in) + (size_t)i * 2;
    float4 a = p[0], b = p[1];
    u16x8 o;
    o[0]=f2bf(a.x); o[1]=f2bf(a.y); o[2]=f2bf(a.z); o[3]=f2bf(a.w);
    o[4]=f2bf(b.x); o[5]=f2bf(b.y); o[6]=f2bf(b.z); o[7]=f2bf(b.w);
    reinterpret_cast<u16x8*>(out)[i] = o;
}

// ---------------------------------------------------------------------------
// fp32 [R][C] -> bf16 [C][R] transpose (weights)
// ---------------------------------------------------------------------------
__global__ __launch_bounds__(256) void transp_bf16(const float* __restrict__ in,
                                                   unsigned short* __restrict__ out,
                                                   int R, int C)
{
    __shared__ float tile[32][33];
    const int c0 = blockIdx.x * 32, r0 = blockIdx.y * 32;
    const int tx = threadIdx.x & 31, ty = threadIdx.x >> 5;
#pragma unroll
    for (int i = 0; i < 32; i += 8)
        tile[ty + i][tx] = in[(size_t)(r0 + ty + i) * C + c0 + tx];
    __syncthreads();
#pragma unroll
    for (int i = 0; i < 32; i += 8)
        out[(size_t)(c0 + ty + i) * R + r0 + tx] = f2bf(tile[tx][ty + i]);
}

// ---------------------------------------------------------------------------
// bf16 MFMA GEMM, 128x128 tile, BK=32, 4 waves, global_load_lds staging.
// A [M][1024] bf16 row-major, Bt [N][1024] bf16 row-major (= B^T). K = 1024.
// LDS linear [128][32] (64B pitch) as required by global_load_lds.
// ---------------------------------------------------------------------------

// QKV: N=3072. Epilogue scatters q (pre-scaled by SC_L2E), k -> [b,h,n,d],
// v -> vt[b,h,d,n].
__global__ __launch_bounds__(256) void gemm_qkv_mfma(const unsigned short* __restrict__ A,
                                                     const unsigned short* __restrict__ Bt,
                                                     unsigned short* __restrict__ qb,
                                                     unsigned short* __restrict__ kb,
                                                     unsigned short* __restrict__ vt)
{
    __shared__ unsigned short As[128][32];
    __shared__ unsigned short Bs[128][32];

    const int t = threadIdx.x;
    const int l = t & 63, w = t >> 6;
    const int wr = w >> 1, wc = w & 1;
    const int g = l >> 4, ql = l & 15;
    const int row0 = blockIdx.y * 128;
    const int col0 = blockIdx.x * 128;
    const int lr = l >> 2, lc = l & 3;     // staging lane mapping

    f32x4 acc[4][4];
#pragma unroll
    for (int mi = 0; mi < 4; ++mi)
#pragma unroll
        for (int ni = 0; ni < 4; ++ni)
#pragma unroll
            for (int r = 0; r < 4; ++r) acc[mi][ni][r] = 0.f;

    for (int k0 = 0; k0 < DIM; k0 += 32) {
        __syncthreads();
        {
            const unsigned short* ag = A  + (size_t)(row0 + 32 * w + lr) * DIM + k0 + lc * 8;
            const unsigned short* bg = Bt + (size_t)(col0 + 32 * w + lr) * DIM + k0 + lc * 8;
            GLDS16(ag,              &As[32 * w][0]);
            GLDS16(ag + 16 * DIM,   &As[32 * w + 16][0]);
            GLDS16(bg,              &Bs[32 * w][0]);
            GLDS16(bg + 16 * DIM,   &Bs[32 * w + 16][0]);
        }
        __syncthreads();

        bf16x8 af[4], bf[4];
#pragma unroll
        for (int mi = 0; mi < 4; ++mi)
            af[mi] = *reinterpret_cast<const bf16x8*>(&As[wr * 64 + mi * 16 + ql][g * 8]);
#pragma unroll
        for (int ni = 0; ni < 4; ++ni)
            bf[ni] = *reinterpret_cast<const bf16x8*>(&Bs[wc * 64 + ni * 16 + ql][g * 8]);
#pragma unroll
        for (int mi = 0; mi < 4; ++mi)
#pragma unroll
            for (int ni = 0; ni < 4; ++ni)
                acc[mi][ni] = __builtin_amdgcn_mfma_f32_16x16x32_bf16(af[mi], bf[ni], acc[mi][ni], 0, 0, 0);
    }

#pragma unroll
    for (int mi = 0; mi < 4; ++mi) {
        const int m0 = row0 + wr * 64 + mi * 16 + g * 4;
        const int b  = m0 >> 11, n0 = m0 & 2047;
#pragma unroll
        for (int ni = 0; ni < 4; ++ni) {
            const int c = col0 + wc * 64 + ni * 16 + ql;
            const int part = c >> 10, inner = c & 1023;
            const int h = inner >> 6, d = inner & 63;
            if (part == 2) {
                u16x4 pk;
#pragma unroll
                for (int r = 0; r < 4; ++r) pk[r] = f2bf(acc[mi][ni][r]);
                *reinterpret_cast<u16x4*>(&vt[(((size_t)b * HEADS + h) * DHEAD + d) * NSEQ + n0]) = pk;
            } else if (part == 0) {
                unsigned short* dst = qb + (((size_t)b * HEADS + h) * NSEQ + n0) * DHEAD + d;
#pragma unroll
                for (int r = 0; r < 4; ++r) dst[(size_t)r * DHEAD] = f2bf(acc[mi][ni][r] * SC_L2E);
            } else {
                unsigned short* dst = kb + (((size_t)b * HEADS + h) * NSEQ + n0) * DHEAD + d;
#pragma unroll
                for (int r = 0; r < 4; ++r) dst[(size_t)r * DHEAD] = f2bf(acc[mi][ni][r]);
            }
        }
    }
}

// out-proj: N=1024, + bias, fp32 out
__global__ __launch_bounds__(256) void gemm_out_mfma(const unsigned short* __restrict__ A,
                                                     const unsigned short* __restrict__ Bt,
                                                     const float* __restrict__ bias,
                                                     float* __restrict__ out)
{
    __shared__ unsigned short As[128][32];
    __shared__ unsigned short Bs[128][32];

    const int t = threadIdx.x;
    const int l = t & 63, w = t >> 6;
    const int wr = w >> 1, wc = w & 1;
    const int g = l >> 4, ql = l & 15;
    const int row0 = blockIdx.y * 128;
    const int col0 = blockIdx.x * 128;
    const int lr = l >> 2, lc = l & 3;

    f32x4 acc[4][4];
#pragma unroll
    for (int mi = 0; mi < 4; ++mi)
#pragma unroll
        for (int ni = 0; ni < 4; ++ni)
#pragma unroll
            for (int r = 0; r < 4; ++r) acc[mi][ni][r] = 0.f;

    for (int k0 = 0; k0 < INNER; k0 += 32) {
        __syncthreads();
        {
            const unsigned short* ag = A  + (size_t)(row0 + 32 * w + lr) * INNER + k0 + lc * 8;
            const unsigned short* bg = Bt + (size_t)(col0 + 32 * w + lr) * INNER + k0 + lc * 8;
            GLDS16(ag,               &As[32 * w][0]);
            GLDS16(ag + 16 * INNER,  &As[32 * w + 16][0]);
            GLDS16(bg,               &Bs[32 * w][0]);
            GLDS16(bg + 16 * INNER,  &Bs[32 * w + 16][0]);
        }
        __syncthreads();

        bf16x8 af[4], bf[4];
#pragma unroll
        for (int mi = 0; mi < 4; ++mi)
            af[mi] = *reinterpret_cast<const bf16x8*>(&As[wr * 64 + mi * 16 + ql][g * 8]);
#pragma unroll
        for (int ni = 0; ni < 4; ++ni)
            bf[ni] = *reinterpret_cast<const bf16x8*>(&Bs[wc * 64 + ni * 16 + ql][g * 8]);
#pragma unroll
        for (int mi = 0; mi < 4; ++mi)
#pragma unroll
            for (int ni = 0; ni < 4; ++ni)
                acc[mi][ni] = __builtin_amdgcn_mfma_f32_16x16x32_bf16(af[mi], bf[ni], acc[mi][ni], 0, 0, 0);
    }

#pragma unroll
    for (int mi = 0; mi < 4; ++mi) {
        const int m0 = row0 + wr * 64 + mi * 16 + g * 4;
#pragma unroll
        for (int ni = 0; ni < 4; ++ni) {
            const int c = col0 + wc * 64 + ni * 16 + ql;
            const float bv = bias[c];
#pragma unroll
            for (int r = 0; r < 4; ++r)
                out[(size_t)(m0 + r) * DIM + c] = acc[mi][ni][r] + bv;
        }
    }
}

// ---------------------------------------------------------------------------
// MFMA flash attention, swapped operands: S^T = K·Q^T, O^T = V^T·P^T.
// Grid (64, 32), 4 waves; wave w owns q-rows w*16..+15 (q = lane&15).
// Q fragments live in registers (no LDS). K/V single-buffered LDS with
// register prefetch of tile t+1 issued before compute of tile t (T14).
// Defer-max online softmax (T13, THR=8 in log2 domain). Q pre-scaled.
// ---------------------------------------------------------------------------
__global__ __launch_bounds__(256) void attn_mfma(const unsigned short* __restrict__ qg,
                                                 const unsigned short* __restrict__ kg,
                                                 const unsigned short* __restrict__ vtg,
                                                 unsigned short* __restrict__ og)
{
    __shared__ unsigned short Ks [64][72];
    __shared__ unsigned short Vts[64][72];   // [d][j]
    __shared__ unsigned short Ps [64][72];   // [q][j]

    const int bh = blockIdx.x;
    const int b = bh >> 4, h = bh & 15;
    const int qblk = blockIdx.y;
    const int t = threadIdx.x, l = t & 63, w = t >> 6;
    const int g = l >> 4, ql = l & 15;

    const size_t hb = (size_t)bh * NSEQ * DHEAD;

    // Q fragments straight from global (pre-scaled by SC_L2E in QKV epilogue)
    const unsigned short* qrow = qg + hb + (size_t)(qblk * 64 + w * 16 + ql) * DHEAD;
    const bf16x8 qf0 = *reinterpret_cast<const bf16x8*>(qrow + g * 8);
    const bf16x8 qf1 = *reinterpret_cast<const bf16x8*>(qrow + 32 + g * 8);

    // staging lane mapping
    const int r = t >> 2, seg = t & 3;
    const unsigned short* kgp = kg  + hb + (size_t)r * DHEAD + seg * 16;
    const unsigned short* vgp = vtg + hb + (size_t)r * NSEQ  + seg * 16;

    // prologue: stage tile 0
    {
        u16x8 k0 = *reinterpret_cast<const u16x8*>(kgp);
        u16x8 k1 = *reinterpret_cast<const u16x8*>(kgp + 8);
        u16x8 v0 = *reinterpret_cast<const u16x8*>(vgp);
        u16x8 v1 = *reinterpret_cast<const u16x8*>(vgp + 8);
        *reinterpret_cast<u16x8*>(&Ks [r][seg * 16])     = k0;
        *reinterpret_cast<u16x8*>(&Ks [r][seg * 16 + 8]) = k1;
        *reinterpret_cast<u16x8*>(&Vts[r][seg * 16])     = v0;
        *reinterpret_cast<u16x8*>(&Vts[r][seg * 16 + 8]) = v1;
    }
    __syncthreads();

    f32x4 acc_o[4];
#pragma unroll
    for (int dt = 0; dt < 4; ++dt)
#pragma unroll
        for (int rr = 0; rr < 4; ++rr) acc_o[dt][rr] = 0.f;
    float m_r = -INFINITY, l_r = 0.f;

    for (int kbi = 0; kbi < NSEQ / 64; ++kbi) {
        // prefetch tile t+1 into registers (latency hides under compute)
        u16x8 nk0, nk1, nv0, nv1;
        const bool pre = (kbi + 1 < NSEQ / 64);
        if (pre) {
            const unsigned short* nkp = kgp + (size_t)(kbi + 1) * 64 * DHEAD;
            const unsigned short* nvp = vgp + (size_t)(kbi + 1) * 64;
            nk0 = *reinterpret_cast<const u16x8*>(nkp);
            nk1 = *reinterpret_cast<const u16x8*>(nkp + 8);
            nv0 = *reinterpret_cast<const u16x8*>(nvp);
            nv1 = *reinterpret_cast<const u16x8*>(nvp + 8);
        }

        // S^T[j][q] = K[j][:]·Q[q][:]  (already scaled, log2 domain)
        f32x4 sacc[4];
#pragma unroll
        for (int jt = 0; jt < 4; ++jt)
#pragma unroll
            for (int rr = 0; rr < 4; ++rr) sacc[jt][rr] = 0.f;
#pragma unroll
        for (int jt = 0; jt < 4; ++jt) {
            bf16x8 kf0 = *reinterpret_cast<const bf16x8*>(&Ks[jt * 16 + ql][g * 8]);
            bf16x8 kf1 = *reinterpret_cast<const bf16x8*>(&Ks[jt * 16 + ql][32 + g * 8]);
            sacc[jt] = __builtin_amdgcn_mfma_f32_16x16x32_bf16(kf0, qf0, sacc[jt], 0, 0, 0);
            sacc[jt] = __builtin_amdgcn_mfma_f32_16x16x32_bf16(kf1, qf1, sacc[jt], 0, 0, 0);
        }

        // online softmax with defer-max (per-lane q-column)
        float sv[16];
#pragma unroll
        for (int jt = 0; jt < 4; ++jt)
#pragma unroll
            for (int rr = 0; rr < 4; ++rr) sv[jt * 4 + rr] = sacc[jt][rr];
        float mx = sv[0];
#pragma unroll
        for (int i = 1; i < 16; ++i) mx = fmaxf(mx, sv[i]);
        mx = fmaxf(mx, __shfl_xor(mx, 16));
        mx = fmaxf(mx, __shfl_xor(mx, 32));
        if (__any(mx > m_r + 8.f)) {            // rescale rarely taken
            const float m_new = fmaxf(m_r, mx);
            const float alpha = fexp2(m_r - m_new);
            l_r *= alpha;
#pragma unroll
            for (int dt = 0; dt < 4; ++dt)
#pragma unroll
                for (int rr = 0; rr < 4; ++rr) acc_o[dt][rr] *= alpha;
            m_r = m_new;
        }
        float p[16], ps = 0.f;
#pragma unroll
        for (int i = 0; i < 16; ++i) { p[i] = fexp2(sv[i] - m_r); ps += p[i]; }
        ps += __shfl_xor(ps, 16);
        ps += __shfl_xor(ps, 32);
        l_r += ps;

        // pack P^T -> Ps[q][j] with v_cvt_pk_bf16_f32 (8B stores)
#pragma unroll
        for (int jt = 0; jt < 4; ++jt) {
            uint2 u;
            u.x = cvtpk(p[jt * 4 + 0], p[jt * 4 + 1]);
            u.y = cvtpk(p[jt * 4 + 2], p[jt * 4 + 3]);
            *reinterpret_cast<uint2*>(&Ps[w * 16 + ql][jt * 16 + g * 4]) = u;
        }

        // O^T[d][q] += Vt[d][:]·P^T[:][q]   (same-wave Ps rows, no barrier)
#pragma unroll
        for (int js = 0; js < 2; ++js) {
            bf16x8 pf = *reinterpret_cast<const bf16x8*>(&Ps[w * 16 + ql][js * 32 + g * 8]);
#pragma unroll
            for (int dt = 0; dt < 4; ++dt) {
                bf16x8 vf = *reinterpret_cast<const bf16x8*>(&Vts[dt * 16 + ql][js * 32 + g * 8]);
                acc_o[dt] = __builtin_amdgcn_mfma_f32_16x16x32_bf16(vf, pf, acc_o[dt], 0, 0, 0);
            }
        }

        __syncthreads();          // all waves done reading Ks/Vts
        if (pre) {
            *reinterpret_cast<u16x8*>(&Ks [r][seg * 16])     = nk0;
            *reinterpret_cast<u16x8*>(&Ks [r][seg * 16 + 8]) = nk1;
            *reinterpret_cast<u16x8*>(&Vts[r][seg * 16])     = nv0;
            *reinterpret_cast<u16x8*>(&Vts[r][seg * 16 + 8]) = nv1;
        }
        __syncthreads();          // new tile visible
    }

    // epilogue: O[b][n][h*64+d], d = dt*16 + g*4 + rr, n = qblk*64 + w*16 + ql
    const float rinv = 1.0f / l_r;
    const int n = qblk * 64 + w * 16 + ql;
    unsigned short* dst = og + ((size_t)b * NSEQ + n) * INNER + h * DHEAD;
#pragma unroll
    for (int dt = 0; dt < 4; ++dt) {
        uint2 u;
        u.x = cvtpk(acc_o[dt][0] * rinv, acc_o[dt][1] * rinv);
        u.y = cvtpk(acc_o[dt][2] * rinv, acc_o[dt][3] * rinv);
        *reinterpret_cast<uint2*>(&dst[dt * 16 + g * 4]) = u;
    }
}

// ---------------------------------------------------------------------------

extern "C" void kernel_launch(void* const* d_in, const int* in_sizes, int n_in,
                              void* d_out, int out_size, void* d_ws, size_t ws_size,
                              hipStream_t stream) {
    const float* x     = (const float*)d_in[0];
    const float* w_qkv = (const float*)d_in[1];
    const float* w_out = (const float*)d_in[2];
    const float* b_out = (const float*)d_in[3];
    float* out = (float*)d_out;

    unsigned short* ws = (unsigned short*)d_ws;
    const size_t nX  = (size_t)MTOT * DIM;
    const size_t nWq = (size_t)DIM * 3 * INNER;
    const size_t nWo = (size_t)DIM * INNER;
    unsigned short* Xb  = ws;
    unsigned short* Wqt = Xb  + nX;
    unsigned short* Wot = Wqt + nWq;
    unsigned short* qb  = Wot + nWo;
    unsigned short* kb  = qb  + nX;
    unsigned short* vt  = kb  + nX;
    unsigned short* Ob  = vt  + nX;

    cvt_bf16<<<dim3(nX / 8 / 256), dim3(256), 0, stream>>>(x, Xb);
    transp_bf16<<<dim3(3 * INNER / 32, DIM / 32), dim3(256), 0, stream>>>(w_qkv, Wqt, DIM, 3 * INNER);
    transp_bf16<<<dim3(DIM / 32, INNER / 32), dim3(256), 0, stream>>>(w_out, Wot, INNER, DIM);

    gemm_qkv_mfma<<<dim3(3 * INNER / 128, MTOT / 128), dim3(256), 0, stream>>>(Xb, Wqt, qb, kb, vt);
    attn_mfma<<<dim3(BATCH * HEADS, NSEQ / 64), dim3(256), 0, stream>>>(qb, kb, vt, Ob);
    gemm_out_mfma<<<dim3(DIM / 128, MTOT / 128), dim3(256), 0, stream>>>(Ob, Wot, b_out, out);
}

// Round 4
// 241.421 us; speedup vs baseline: 18.5160x; 1.0365x over previous
//
#include <hip/hip_runtime.h>
#include <math.h>

#define BATCH   4
#define NSEQ    2048
#define DIM     1024
#define HEADS   16
#define DHEAD   64
#define INNER   1024
#define MTOT    (BATCH*NSEQ)     // 8192
// softmax in log2 domain: SCALE * log2(e), folded into Q at QKV epilogue
#define SC_L2E  0.04508422f

typedef __attribute__((ext_vector_type(8))) unsigned short u16x8;
typedef __attribute__((ext_vector_type(4))) unsigned short u16x4;
typedef __attribute__((ext_vector_type(8))) short          bf16x8;
typedef __attribute__((ext_vector_type(4))) float          f32x4;

__device__ __forceinline__ unsigned short f2bf(float f) {
    unsigned int u = __builtin_bit_cast(unsigned int, f);
    u += 0x7FFFu + ((u >> 16) & 1u);       // RNE
    return (unsigned short)(u >> 16);
}

__device__ __forceinline__ float fexp2(float x) {
    float r; asm("v_exp_f32 %0, %1" : "=v"(r) : "v"(x)); return r;
}

__device__ __forceinline__ unsigned int cvtpk(float lo, float hi) {
    unsigned int r; asm("v_cvt_pk_bf16_f32 %0, %1, %2" : "=v"(r) : "v"(lo), "v"(hi));
    return r;
}

// async global->LDS, 16B per lane; lds base must be wave-uniform
#define GLDS16(gp, lp) __builtin_amdgcn_global_load_lds( \
    (const __attribute__((address_space(1))) unsigned int*)(gp), \
    (__attribute__((address_space(3))) unsigned int*)(lp), 16, 0, 0)

// XOR swizzle: ushort column c (0..63) within row r -> permute 16B slots.
// Spreads the 16-row x fixed-slot ds_read_b128 pattern across all 8 slots.
#define SWC(r, c) ((c) ^ (((r) & 7) << 3))

// ---------------------------------------------------------------------------
// fp32 -> bf16 elementwise convert (x)
// ---------------------------------------------------------------------------
__global__ __launch_bounds__(256) void cvt_bf16(const float* __restrict__ in,
                                                unsigned short* __restrict__ out)
{
    const int i = blockIdx.x * 256 + threadIdx.x;
    const float4* p = reinterpret_cast<const float4*>(in) + (size_t)i * 2;
    float4 a = p[0], b = p[1];
    u16x8 o;
    o[0]=f2bf(a.x); o[1]=f2bf(a.y); o[2]=f2bf(a.z); o[3]=f2bf(a.w);
    o[4]=f2bf(b.x); o[5]=f2bf(b.y); o[6]=f2bf(b.z); o[7]=f2bf(b.w);
    reinterpret_cast<u16x8*>(out)[i] = o;
}

// ---------------------------------------------------------------------------
// fp32 [R][C] -> bf16 [C][R] transpose (weights)
// ---------------------------------------------------------------------------
__global__ __launch_bounds__(256) void transp_bf16(const float* __restrict__ in,
                                                   unsigned short* __restrict__ out,
                                                   int R, int C)
{
    __shared__ float tile[32][33];
    const int c0 = blockIdx.x * 32, r0 = blockIdx.y * 32;
    const int tx = threadIdx.x & 31, ty = threadIdx.x >> 5;
#pragma unroll
    for (int i = 0; i < 32; i += 8)
        tile[ty + i][tx] = in[(size_t)(r0 + ty + i) * C + c0 + tx];
    __syncthreads();
#pragma unroll
    for (int i = 0; i < 32; i += 8)
        out[(size_t)(c0 + ty + i) * R + r0 + tx] = f2bf(tile[tx][ty + i]);
}

// ---------------------------------------------------------------------------
// bf16 MFMA GEMM, 128x128 tile, BK=32, 4 waves, global_load_lds staging.
// ---------------------------------------------------------------------------

// QKV: N=3072. Epilogue scatters q (pre-scaled by SC_L2E), k -> [b,h,n,d],
// v -> vt[b,h,d,n].
__global__ __launch_bounds__(256) void gemm_qkv_mfma(const unsigned short* __restrict__ A,
                                                     const unsigned short* __restrict__ Bt,
                                                     unsigned short* __restrict__ qb,
                                                     unsigned short* __restrict__ kb,
                                                     unsigned short* __restrict__ vt)
{
    __shared__ unsigned short As[128][32];
    __shared__ unsigned short Bs[128][32];

    const int t = threadIdx.x;
    const int l = t & 63, w = t >> 6;
    const int wr = w >> 1, wc = w & 1;
    const int g = l >> 4, ql = l & 15;
    const int row0 = blockIdx.y * 128;
    const int col0 = blockIdx.x * 128;
    const int lr = l >> 2, lc = l & 3;     // staging lane mapping

    f32x4 acc[4][4];
#pragma unroll
    for (int mi = 0; mi < 4; ++mi)
#pragma unroll
        for (int ni = 0; ni < 4; ++ni)
#pragma unroll
            for (int r = 0; r < 4; ++r) acc[mi][ni][r] = 0.f;

    for (int k0 = 0; k0 < DIM; k0 += 32) {
        __syncthreads();
        {
            const unsigned short* ag = A  + (size_t)(row0 + 32 * w + lr) * DIM + k0 + lc * 8;
            const unsigned short* bg = Bt + (size_t)(col0 + 32 * w + lr) * DIM + k0 + lc * 8;
            GLDS16(ag,              &As[32 * w][0]);
            GLDS16(ag + 16 * DIM,   &As[32 * w + 16][0]);
            GLDS16(bg,              &Bs[32 * w][0]);
            GLDS16(bg + 16 * DIM,   &Bs[32 * w + 16][0]);
        }
        __syncthreads();

        bf16x8 af[4], bf[4];
#pragma unroll
        for (int mi = 0; mi < 4; ++mi)
            af[mi] = *reinterpret_cast<const bf16x8*>(&As[wr * 64 + mi * 16 + ql][g * 8]);
#pragma unroll
        for (int ni = 0; ni < 4; ++ni)
            bf[ni] = *reinterpret_cast<const bf16x8*>(&Bs[wc * 64 + ni * 16 + ql][g * 8]);
#pragma unroll
        for (int mi = 0; mi < 4; ++mi)
#pragma unroll
            for (int ni = 0; ni < 4; ++ni)
                acc[mi][ni] = __builtin_amdgcn_mfma_f32_16x16x32_bf16(af[mi], bf[ni], acc[mi][ni], 0, 0, 0);
    }

#pragma unroll
    for (int mi = 0; mi < 4; ++mi) {
        const int m0 = row0 + wr * 64 + mi * 16 + g * 4;
        const int b  = m0 >> 11, n0 = m0 & 2047;
#pragma unroll
        for (int ni = 0; ni < 4; ++ni) {
            const int c = col0 + wc * 64 + ni * 16 + ql;
            const int part = c >> 10, inner = c & 1023;
            const int h = inner >> 6, d = inner & 63;
            if (part == 2) {
                u16x4 pk;
#pragma unroll
                for (int r = 0; r < 4; ++r) pk[r] = f2bf(acc[mi][ni][r]);
                *reinterpret_cast<u16x4*>(&vt[(((size_t)b * HEADS + h) * DHEAD + d) * NSEQ + n0]) = pk;
            } else if (part == 0) {
                unsigned short* dst = qb + (((size_t)b * HEADS + h) * NSEQ + n0) * DHEAD + d;
#pragma unroll
                for (int r = 0; r < 4; ++r) dst[(size_t)r * DHEAD] = f2bf(acc[mi][ni][r] * SC_L2E);
            } else {
                unsigned short* dst = kb + (((size_t)b * HEADS + h) * NSEQ + n0) * DHEAD + d;
#pragma unroll
                for (int r = 0; r < 4; ++r) dst[(size_t)r * DHEAD] = f2bf(acc[mi][ni][r]);
            }
        }
    }
}

// out-proj: N=1024, + bias, fp32 out
__global__ __launch_bounds__(256) void gemm_out_mfma(const unsigned short* __restrict__ A,
                                                     const unsigned short* __restrict__ Bt,
                                                     const float* __restrict__ bias,
                                                     float* __restrict__ out)
{
    __shared__ unsigned short As[128][32];
    __shared__ unsigned short Bs[128][32];

    const int t = threadIdx.x;
    const int l = t & 63, w = t >> 6;
    const int wr = w >> 1, wc = w & 1;
    const int g = l >> 4, ql = l & 15;
    const int row0 = blockIdx.y * 128;
    const int col0 = blockIdx.x * 128;
    const int lr = l >> 2, lc = l & 3;

    f32x4 acc[4][4];
#pragma unroll
    for (int mi = 0; mi < 4; ++mi)
#pragma unroll
        for (int ni = 0; ni < 4; ++ni)
#pragma unroll
            for (int r = 0; r < 4; ++r) acc[mi][ni][r] = 0.f;

    for (int k0 = 0; k0 < INNER; k0 += 32) {
        __syncthreads();
        {
            const unsigned short* ag = A  + (size_t)(row0 + 32 * w + lr) * INNER + k0 + lc * 8;
            const unsigned short* bg = Bt + (size_t)(col0 + 32 * w + lr) * INNER + k0 + lc * 8;
            GLDS16(ag,               &As[32 * w][0]);
            GLDS16(ag + 16 * INNER,  &As[32 * w + 16][0]);
            GLDS16(bg,               &Bs[32 * w][0]);
            GLDS16(bg + 16 * INNER,  &Bs[32 * w + 16][0]);
        }
        __syncthreads();

        bf16x8 af[4], bf[4];
#pragma unroll
        for (int mi = 0; mi < 4; ++mi)
            af[mi] = *reinterpret_cast<const bf16x8*>(&As[wr * 64 + mi * 16 + ql][g * 8]);
#pragma unroll
        for (int ni = 0; ni < 4; ++ni)
            bf[ni] = *reinterpret_cast<const bf16x8*>(&Bs[wc * 64 + ni * 16 + ql][g * 8]);
#pragma unroll
        for (int mi = 0; mi < 4; ++mi)
#pragma unroll
            for (int ni = 0; ni < 4; ++ni)
                acc[mi][ni] = __builtin_amdgcn_mfma_f32_16x16x32_bf16(af[mi], bf[ni], acc[mi][ni], 0, 0, 0);
    }

#pragma unroll
    for (int mi = 0; mi < 4; ++mi) {
        const int m0 = row0 + wr * 64 + mi * 16 + g * 4;
#pragma unroll
        for (int ni = 0; ni < 4; ++ni) {
            const int c = col0 + wc * 64 + ni * 16 + ql;
            const float bv = bias[c];
#pragma unroll
            for (int r = 0; r < 4; ++r)
                out[(size_t)(m0 + r) * DIM + c] = acc[mi][ni][r] + bv;
        }
    }
}

// ---------------------------------------------------------------------------
// MFMA flash attention, swapped operands: S^T = K·Q^T, O^T = V^T·P^T.
// Grid (64, 32), 4 waves; wave w owns q-rows w*16..+15 (q = lane&15).
// K/V double-buffered in XOR-swizzled [64][64] LDS (T2); prefetched tile
// written to the alternate buffer -> single barrier per tile. T5 setprio
// around MFMA clusters. Defer-max softmax (T13). Q pre-scaled by SC_L2E.
// ---------------------------------------------------------------------------
__global__ __launch_bounds__(256) void attn_mfma(const unsigned short* __restrict__ qg,
                                                 const unsigned short* __restrict__ kg,
                                                 const unsigned short* __restrict__ vtg,
                                                 unsigned short* __restrict__ og)
{
    __shared__ unsigned short Ks [2][64 * 64];
    __shared__ unsigned short Vts[2][64 * 64];   // [d][j]
    __shared__ unsigned short Ps [64 * 64];      // [q][j]

    const int bh = blockIdx.x;
    const int b = bh >> 4, h = bh & 15;
    const int qblk = blockIdx.y;
    const int t = threadIdx.x, l = t & 63, w = t >> 6;
    const int g = l >> 4, ql = l & 15;

    const size_t hb = (size_t)bh * NSEQ * DHEAD;

    // Q fragments straight from global (pre-scaled)
    const unsigned short* qrow = qg + hb + (size_t)(qblk * 64 + w * 16 + ql) * DHEAD;
    const bf16x8 qf0 = *reinterpret_cast<const bf16x8*>(qrow + g * 8);
    const bf16x8 qf1 = *reinterpret_cast<const bf16x8*>(qrow + 32 + g * 8);

    // staging lane mapping: row r, two 16B chunks at cols seg*16, seg*16+8
    const int r = t >> 2, seg = t & 3;
    const unsigned short* kgp = kg  + hb + (size_t)r * DHEAD + seg * 16;
    const unsigned short* vgp = vtg + hb + (size_t)r * NSEQ  + seg * 16;
    const int st0 = r * 64 + SWC(r, seg * 16);       // swizzled write offsets
    const int st1 = r * 64 + SWC(r, seg * 16 + 8);

    // prologue: stage tile 0 into buffer 0
    {
        u16x8 k0 = *reinterpret_cast<const u16x8*>(kgp);
        u16x8 k1 = *reinterpret_cast<const u16x8*>(kgp + 8);
        u16x8 v0 = *reinterpret_cast<const u16x8*>(vgp);
        u16x8 v1 = *reinterpret_cast<const u16x8*>(vgp + 8);
        *reinterpret_cast<u16x8*>(&Ks [0][st0]) = k0;
        *reinterpret_cast<u16x8*>(&Ks [0][st1]) = k1;
        *reinterpret_cast<u16x8*>(&Vts[0][st0]) = v0;
        *reinterpret_cast<u16x8*>(&Vts[0][st1]) = v1;
    }
    __syncthreads();

    f32x4 acc_o[4];
#pragma unroll
    for (int dt = 0; dt < 4; ++dt)
#pragma unroll
        for (int rr = 0; rr < 4; ++rr) acc_o[dt][rr] = 0.f;
    float m_r = -INFINITY, l_r = 0.f;

    const int qrl = w * 16 + ql;        // this lane's P row

    for (int kbi = 0; kbi < NSEQ / 64; ++kbi) {
        const int cur = kbi & 1;
        // prefetch tile t+1 into registers
        u16x8 nk0, nk1, nv0, nv1;
        const bool pre = (kbi + 1 < NSEQ / 64);
        if (pre) {
            const unsigned short* nkp = kgp + (size_t)(kbi + 1) * 64 * DHEAD;
            const unsigned short* nvp = vgp + (size_t)(kbi + 1) * 64;
            nk0 = *reinterpret_cast<const u16x8*>(nkp);
            nk1 = *reinterpret_cast<const u16x8*>(nkp + 8);
            nv0 = *reinterpret_cast<const u16x8*>(nvp);
            nv1 = *reinterpret_cast<const u16x8*>(nvp + 8);
        }

        // S^T[j][q] = K[j][:]·Q[q][:]  (log2 domain, pre-scaled)
        f32x4 sacc[4];
#pragma unroll
        for (int jt = 0; jt < 4; ++jt)
#pragma unroll
            for (int rr = 0; rr < 4; ++rr) sacc[jt][rr] = 0.f;
        __builtin_amdgcn_s_setprio(1);
#pragma unroll
        for (int jt = 0; jt < 4; ++jt) {
            const int row = jt * 16 + ql;
            bf16x8 kf0 = *reinterpret_cast<const bf16x8*>(&Ks[cur][row * 64 + SWC(row, g * 8)]);
            bf16x8 kf1 = *reinterpret_cast<const bf16x8*>(&Ks[cur][row * 64 + SWC(row, 32 + g * 8)]);
            sacc[jt] = __builtin_amdgcn_mfma_f32_16x16x32_bf16(kf0, qf0, sacc[jt], 0, 0, 0);
            sacc[jt] = __builtin_amdgcn_mfma_f32_16x16x32_bf16(kf1, qf1, sacc[jt], 0, 0, 0);
        }
        __builtin_amdgcn_s_setprio(0);

        // online softmax with defer-max (per-lane q-column), tree reductions
        float sv[16];
#pragma unroll
        for (int jt = 0; jt < 4; ++jt)
#pragma unroll
            for (int rr = 0; rr < 4; ++rr) sv[jt * 4 + rr] = sacc[jt][rr];
        float m0a = fmaxf(sv[0], sv[1]),  m1a = fmaxf(sv[2], sv[3]);
        float m2a = fmaxf(sv[4], sv[5]),  m3a = fmaxf(sv[6], sv[7]);
        float m4a = fmaxf(sv[8], sv[9]),  m5a = fmaxf(sv[10], sv[11]);
        float m6a = fmaxf(sv[12], sv[13]), m7a = fmaxf(sv[14], sv[15]);
        m0a = fmaxf(m0a, m1a); m2a = fmaxf(m2a, m3a);
        m4a = fmaxf(m4a, m5a); m6a = fmaxf(m6a, m7a);
        float mx = fmaxf(fmaxf(m0a, m2a), fmaxf(m4a, m6a));
        mx = fmaxf(mx, __shfl_xor(mx, 16));
        mx = fmaxf(mx, __shfl_xor(mx, 32));
        if (__any(mx > m_r + 8.f)) {
            const float m_new = fmaxf(m_r, mx);
            const float alpha = fexp2(m_r - m_new);
            l_r *= alpha;
#pragma unroll
            for (int dt = 0; dt < 4; ++dt)
#pragma unroll
                for (int rr = 0; rr < 4; ++rr) acc_o[dt][rr] *= alpha;
            m_r = m_new;
        }
        float p[16];
#pragma unroll
        for (int i = 0; i < 16; ++i) p[i] = fexp2(sv[i] - m_r);
        float s0 = (p[0] + p[1]) + (p[2] + p[3]);
        float s1 = (p[4] + p[5]) + (p[6] + p[7]);
        float s2 = (p[8] + p[9]) + (p[10] + p[11]);
        float s3 = (p[12] + p[13]) + (p[14] + p[15]);
        float ps = (s0 + s1) + (s2 + s3);
        ps += __shfl_xor(ps, 16);
        ps += __shfl_xor(ps, 32);
        l_r += ps;

        // pack P^T -> Ps[q][j] (8B swizzled stores)
#pragma unroll
        for (int jt = 0; jt < 4; ++jt) {
            uint2 u;
            u.x = cvtpk(p[jt * 4 + 0], p[jt * 4 + 1]);
            u.y = cvtpk(p[jt * 4 + 2], p[jt * 4 + 3]);
            *reinterpret_cast<uint2*>(&Ps[qrl * 64 + SWC(qrl, jt * 16 + g * 4)]) = u;
        }

        // O^T[d][q] += Vt[d][:]·P^T[:][q]   (same-wave Ps rows, no barrier)
        __builtin_amdgcn_s_setprio(1);
#pragma unroll
        for (int js = 0; js < 2; ++js) {
            bf16x8 pf = *reinterpret_cast<const bf16x8*>(&Ps[qrl * 64 + SWC(qrl, js * 32 + g * 8)]);
#pragma unroll
            for (int dt = 0; dt < 4; ++dt) {
                const int row = dt * 16 + ql;
                bf16x8 vf = *reinterpret_cast<const bf16x8*>(&Vts[cur][row * 64 + SWC(row, js * 32 + g * 8)]);
                acc_o[dt] = __builtin_amdgcn_mfma_f32_16x16x32_bf16(vf, pf, acc_o[dt], 0, 0, 0);
            }
        }
        __builtin_amdgcn_s_setprio(0);

        // stage tile t+1 into the alternate buffer (no wait on readers of cur)
        if (pre) {
            *reinterpret_cast<u16x8*>(&Ks [cur ^ 1][st0]) = nk0;
            *reinterpret_cast<u16x8*>(&Ks [cur ^ 1][st1]) = nk1;
            *reinterpret_cast<u16x8*>(&Vts[cur ^ 1][st0]) = nv0;
            *reinterpret_cast<u16x8*>(&Vts[cur ^ 1][st1]) = nv1;
        }
        __syncthreads();          // new tile visible; cur readers all done
    }

    // epilogue: O[b][n][h*64+d], d = dt*16 + g*4 + rr, n = qblk*64 + qrl
    const float rinv = 1.0f / l_r;
    const int n = qblk * 64 + qrl;
    unsigned short* dst = og + ((size_t)b * NSEQ + n) * INNER + h * DHEAD;
#pragma unroll
    for (int dt = 0; dt < 4; ++dt) {
        uint2 u;
        u.x = cvtpk(acc_o[dt][0] * rinv, acc_o[dt][1] * rinv);
        u.y = cvtpk(acc_o[dt][2] * rinv, acc_o[dt][3] * rinv);
        *reinterpret_cast<uint2*>(&dst[dt * 16 + g * 4]) = u;
    }
}

// ---------------------------------------------------------------------------

extern "C" void kernel_launch(void* const* d_in, const int* in_sizes, int n_in,
                              void* d_out, int out_size, void* d_ws, size_t ws_size,
                              hipStream_t stream) {
    const float* x     = (const float*)d_in[0];
    const float* w_qkv = (const float*)d_in[1];
    const float* w_out = (const float*)d_in[2];
    const float* b_out = (const float*)d_in[3];
    float* out = (float*)d_out;

    unsigned short* ws = (unsigned short*)d_ws;
    const size_t nX  = (size_t)MTOT * DIM;
    const size_t nWq = (size_t)DIM * 3 * INNER;
    const size_t nWo = (size_t)DIM * INNER;
    unsigned short* Xb  = ws;
    unsigned short* Wqt = Xb  + nX;
    unsigned short* Wot = Wqt + nWq;
    unsigned short* qb  = Wot + nWo;
    unsigned short* kb  = qb  + nX;
    unsigned short* vt  = kb  + nX;
    unsigned short* Ob  = vt  + nX;

    cvt_bf16<<<dim3(nX / 8 / 256), dim3(256), 0, stream>>>(x, Xb);
    transp_bf16<<<dim3(3 * INNER / 32, DIM / 32), dim3(256), 0, stream>>>(w_qkv, Wqt, DIM, 3 * INNER);
    transp_bf16<<<dim3(DIM / 32, INNER / 32), dim3(256), 0, stream>>>(w_out, Wot, INNER, DIM);

    gemm_qkv_mfma<<<dim3(3 * INNER / 128, MTOT / 128), dim3(256), 0, stream>>>(Xb, Wqt, qb, kb, vt);
    attn_mfma<<<dim3(BATCH * HEADS, NSEQ / 64), dim3(256), 0, stream>>>(qb, kb, vt, Ob);
    gemm_out_mfma<<<dim3(DIM / 128, MTOT / 128), dim3(256), 0, stream>>>(Ob, Wot, b_out, out);
}

// Round 5
// 234.585 us; speedup vs baseline: 19.0556x; 1.0291x over previous
//
#include <hip/hip_runtime.h>
#include <math.h>

#define BATCH   4
#define NSEQ    2048
#define DIM     1024
#define HEADS   16
#define DHEAD   64
#define INNER   1024
#define MTOT    (BATCH*NSEQ)     // 8192
// softmax in log2 domain: SCALE * log2(e), folded into Q at QKV epilogue
#define SC_L2E  0.04508422f

typedef __attribute__((ext_vector_type(8))) unsigned short u16x8;
typedef __attribute__((ext_vector_type(4))) unsigned short u16x4;
typedef __attribute__((ext_vector_type(8))) short          bf16x8;
typedef __attribute__((ext_vector_type(4))) float          f32x4;

__device__ __forceinline__ unsigned short f2bf(float f) {
    unsigned int u = __builtin_bit_cast(unsigned int, f);
    u += 0x7FFFu + ((u >> 16) & 1u);       // RNE
    return (unsigned short)(u >> 16);
}

__device__ __forceinline__ float fexp2(float x) {
    float r; asm("v_exp_f32 %0, %1" : "=v"(r) : "v"(x)); return r;
}

__device__ __forceinline__ unsigned int cvtpk(float lo, float hi) {
    unsigned int r; asm("v_cvt_pk_bf16_f32 %0, %1, %2" : "=v"(r) : "v"(lo), "v"(hi));
    return r;
}

// async global->LDS, 16B per lane; lds base must be wave-uniform
#define GLDS16(gp, lp) __builtin_amdgcn_global_load_lds( \
    (const __attribute__((address_space(1))) unsigned int*)(gp), \
    (__attribute__((address_space(3))) unsigned int*)(lp), 16, 0, 0)

// XOR swizzle: ushort column c (0..63) within row r -> permute 16B slots.
#define SWC(r, c) ((c) ^ (((r) & 7) << 3))

// ---------------------------------------------------------------------------
// fp32 -> bf16 elementwise convert (x)
// ---------------------------------------------------------------------------
__global__ __launch_bounds__(256) void cvt_bf16(const float* __restrict__ in,
                                                unsigned short* __restrict__ out)
{
    const int i = blockIdx.x * 256 + threadIdx.x;
    const float4* p = reinterpret_cast<const float4*>(in) + (size_t)i * 2;
    float4 a = p[0], b = p[1];
    u16x8 o;
    o[0]=f2bf(a.x); o[1]=f2bf(a.y); o[2]=f2bf(a.z); o[3]=f2bf(a.w);
    o[4]=f2bf(b.x); o[5]=f2bf(b.y); o[6]=f2bf(b.z); o[7]=f2bf(b.w);
    reinterpret_cast<u16x8*>(out)[i] = o;
}

// ---------------------------------------------------------------------------
// fp32 [R][C] -> bf16 [C][R] transpose (weights)
// ---------------------------------------------------------------------------
__global__ __launch_bounds__(256) void transp_bf16(const float* __restrict__ in,
                                                   unsigned short* __restrict__ out,
                                                   int R, int C)
{
    __shared__ float tile[32][33];
    const int c0 = blockIdx.x * 32, r0 = blockIdx.y * 32;
    const int tx = threadIdx.x & 31, ty = threadIdx.x >> 5;
#pragma unroll
    for (int i = 0; i < 32; i += 8)
        tile[ty + i][tx] = in[(size_t)(r0 + ty + i) * C + c0 + tx];
    __syncthreads();
#pragma unroll
    for (int i = 0; i < 32; i += 8)
        out[(size_t)(c0 + ty + i) * R + r0 + tx] = f2bf(tile[tx][ty + i]);
}

// ---------------------------------------------------------------------------
// bf16 MFMA GEMM, 128x128 tile, BK=32, 4 waves, global_load_lds staging.
// ---------------------------------------------------------------------------

// QKV: N=3072. Epilogue scatters q (pre-scaled by SC_L2E), k -> [b,h,n,d],
// v -> vt[b,h,d,n].
__global__ __launch_bounds__(256) void gemm_qkv_mfma(const unsigned short* __restrict__ A,
                                                     const unsigned short* __restrict__ Bt,
                                                     unsigned short* __restrict__ qb,
                                                     unsigned short* __restrict__ kb,
                                                     unsigned short* __restrict__ vt)
{
    __shared__ unsigned short As[128][32];
    __shared__ unsigned short Bs[128][32];

    const int t = threadIdx.x;
    const int l = t & 63, w = t >> 6;
    const int wr = w >> 1, wc = w & 1;
    const int g = l >> 4, ql = l & 15;
    const int row0 = blockIdx.y * 128;
    const int col0 = blockIdx.x * 128;
    const int lr = l >> 2, lc = l & 3;     // staging lane mapping

    f32x4 acc[4][4];
#pragma unroll
    for (int mi = 0; mi < 4; ++mi)
#pragma unroll
        for (int ni = 0; ni < 4; ++ni)
#pragma unroll
            for (int r = 0; r < 4; ++r) acc[mi][ni][r] = 0.f;

    for (int k0 = 0; k0 < DIM; k0 += 32) {
        __syncthreads();
        {
            const unsigned short* ag = A  + (size_t)(row0 + 32 * w + lr) * DIM + k0 + lc * 8;
            const unsigned short* bg = Bt + (size_t)(col0 + 32 * w + lr) * DIM + k0 + lc * 8;
            GLDS16(ag,              &As[32 * w][0]);
            GLDS16(ag + 16 * DIM,   &As[32 * w + 16][0]);
            GLDS16(bg,              &Bs[32 * w][0]);
            GLDS16(bg + 16 * DIM,   &Bs[32 * w + 16][0]);
        }
        __syncthreads();

        bf16x8 af[4], bf[4];
#pragma unroll
        for (int mi = 0; mi < 4; ++mi)
            af[mi] = *reinterpret_cast<const bf16x8*>(&As[wr * 64 + mi * 16 + ql][g * 8]);
#pragma unroll
        for (int ni = 0; ni < 4; ++ni)
            bf[ni] = *reinterpret_cast<const bf16x8*>(&Bs[wc * 64 + ni * 16 + ql][g * 8]);
#pragma unroll
        for (int mi = 0; mi < 4; ++mi)
#pragma unroll
            for (int ni = 0; ni < 4; ++ni)
                acc[mi][ni] = __builtin_amdgcn_mfma_f32_16x16x32_bf16(af[mi], bf[ni], acc[mi][ni], 0, 0, 0);
    }

#pragma unroll
    for (int mi = 0; mi < 4; ++mi) {
        const int m0 = row0 + wr * 64 + mi * 16 + g * 4;
        const int b  = m0 >> 11, n0 = m0 & 2047;
#pragma unroll
        for (int ni = 0; ni < 4; ++ni) {
            const int c = col0 + wc * 64 + ni * 16 + ql;
            const int part = c >> 10, inner = c & 1023;
            const int h = inner >> 6, d = inner & 63;
            if (part == 2) {
                u16x4 pk;
#pragma unroll
                for (int r = 0; r < 4; ++r) pk[r] = f2bf(acc[mi][ni][r]);
                *reinterpret_cast<u16x4*>(&vt[(((size_t)b * HEADS + h) * DHEAD + d) * NSEQ + n0]) = pk;
            } else if (part == 0) {
                unsigned short* dst = qb + (((size_t)b * HEADS + h) * NSEQ + n0) * DHEAD + d;
#pragma unroll
                for (int r = 0; r < 4; ++r) dst[(size_t)r * DHEAD] = f2bf(acc[mi][ni][r] * SC_L2E);
            } else {
                unsigned short* dst = kb + (((size_t)b * HEADS + h) * NSEQ + n0) * DHEAD + d;
#pragma unroll
                for (int r = 0; r < 4; ++r) dst[(size_t)r * DHEAD] = f2bf(acc[mi][ni][r]);
            }
        }
    }
}

// out-proj: N=1024, + bias, fp32 out
__global__ __launch_bounds__(256) void gemm_out_mfma(const unsigned short* __restrict__ A,
                                                     const unsigned short* __restrict__ Bt,
                                                     const float* __restrict__ bias,
                                                     float* __restrict__ out)
{
    __shared__ unsigned short As[128][32];
    __shared__ unsigned short Bs[128][32];

    const int t = threadIdx.x;
    const int l = t & 63, w = t >> 6;
    const int wr = w >> 1, wc = w & 1;
    const int g = l >> 4, ql = l & 15;
    const int row0 = blockIdx.y * 128;
    const int col0 = blockIdx.x * 128;
    const int lr = l >> 2, lc = l & 3;

    f32x4 acc[4][4];
#pragma unroll
    for (int mi = 0; mi < 4; ++mi)
#pragma unroll
        for (int ni = 0; ni < 4; ++ni)
#pragma unroll
            for (int r = 0; r < 4; ++r) acc[mi][ni][r] = 0.f;

    for (int k0 = 0; k0 < INNER; k0 += 32) {
        __syncthreads();
        {
            const unsigned short* ag = A  + (size_t)(row0 + 32 * w + lr) * INNER + k0 + lc * 8;
            const unsigned short* bg = Bt + (size_t)(col0 + 32 * w + lr) * INNER + k0 + lc * 8;
            GLDS16(ag,               &As[32 * w][0]);
            GLDS16(ag + 16 * INNER,  &As[32 * w + 16][0]);
            GLDS16(bg,               &Bs[32 * w][0]);
            GLDS16(bg + 16 * INNER,  &Bs[32 * w + 16][0]);
        }
        __syncthreads();

        bf16x8 af[4], bf[4];
#pragma unroll
        for (int mi = 0; mi < 4; ++mi)
            af[mi] = *reinterpret_cast<const bf16x8*>(&As[wr * 64 + mi * 16 + ql][g * 8]);
#pragma unroll
        for (int ni = 0; ni < 4; ++ni)
            bf[ni] = *reinterpret_cast<const bf16x8*>(&Bs[wc * 64 + ni * 16 + ql][g * 8]);
#pragma unroll
        for (int mi = 0; mi < 4; ++mi)
#pragma unroll
            for (int ni = 0; ni < 4; ++ni)
                acc[mi][ni] = __builtin_amdgcn_mfma_f32_16x16x32_bf16(af[mi], bf[ni], acc[mi][ni], 0, 0, 0);
    }

#pragma unroll
    for (int mi = 0; mi < 4; ++mi) {
        const int m0 = row0 + wr * 64 + mi * 16 + g * 4;
#pragma unroll
        for (int ni = 0; ni < 4; ++ni) {
            const int c = col0 + wc * 64 + ni * 16 + ql;
            const float bv = bias[c];
#pragma unroll
            for (int r = 0; r < 4; ++r)
                out[(size_t)(m0 + r) * DIM + c] = acc[mi][ni][r] + bv;
        }
    }
}

// ---------------------------------------------------------------------------
// MFMA flash attention, swapped operands: S^T = K·Q^T, O^T = V^T·P^T.
// Wq=32: each wave owns 32 q-rows (2 q-halves), QBLK=128/block, 4 waves.
// K/V fragments are read once per wave-tile and reused across both q-halves
// -> 1.7x less LDS traffic per FLOP than Wq=16. Grid (64, 16).
// K/V double-buffered XOR-swizzled LDS; T5 setprio; defer-max (T13).
// ---------------------------------------------------------------------------
__global__ __launch_bounds__(256) void attn_mfma(const unsigned short* __restrict__ qg,
                                                 const unsigned short* __restrict__ kg,
                                                 const unsigned short* __restrict__ vtg,
                                                 unsigned short* __restrict__ og)
{
    __shared__ unsigned short Ks [2][64 * 64];
    __shared__ unsigned short Vts[2][64 * 64];   // [d][j]
    __shared__ unsigned short Ps [128 * 64];     // [q][j]

    const int bh = blockIdx.x;
    const int b = bh >> 4, h = bh & 15;
    const int qblk = blockIdx.y;
    const int t = threadIdx.x, l = t & 63, w = t >> 6;
    const int g = l >> 4, ql = l & 15;

    const size_t hb = (size_t)bh * NSEQ * DHEAD;

    // Q fragments for both q-halves (pre-scaled by SC_L2E)
    bf16x8 qf[2][2];
#pragma unroll
    for (int qh = 0; qh < 2; ++qh) {
        const unsigned short* qrow = qg + hb + (size_t)(qblk * 128 + w * 32 + qh * 16 + ql) * DHEAD;
        qf[qh][0] = *reinterpret_cast<const bf16x8*>(qrow + g * 8);
        qf[qh][1] = *reinterpret_cast<const bf16x8*>(qrow + 32 + g * 8);
    }

    // staging lane mapping: row r, two 16B chunks at cols seg*16, seg*16+8
    const int r = t >> 2, seg = t & 3;
    const unsigned short* kgp = kg  + hb + (size_t)r * DHEAD + seg * 16;
    const unsigned short* vgp = vtg + hb + (size_t)r * NSEQ  + seg * 16;
    const int st0 = r * 64 + SWC(r, seg * 16);
    const int st1 = r * 64 + SWC(r, seg * 16 + 8);

    // prologue: stage tile 0 into buffer 0
    {
        u16x8 k0 = *reinterpret_cast<const u16x8*>(kgp);
        u16x8 k1 = *reinterpret_cast<const u16x8*>(kgp + 8);
        u16x8 v0 = *reinterpret_cast<const u16x8*>(vgp);
        u16x8 v1 = *reinterpret_cast<const u16x8*>(vgp + 8);
        *reinterpret_cast<u16x8*>(&Ks [0][st0]) = k0;
        *reinterpret_cast<u16x8*>(&Ks [0][st1]) = k1;
        *reinterpret_cast<u16x8*>(&Vts[0][st0]) = v0;
        *reinterpret_cast<u16x8*>(&Vts[0][st1]) = v1;
    }
    __syncthreads();

    f32x4 acc_o[2][4];
#pragma unroll
    for (int qh = 0; qh < 2; ++qh)
#pragma unroll
        for (int dt = 0; dt < 4; ++dt)
#pragma unroll
            for (int rr = 0; rr < 4; ++rr) acc_o[qh][dt][rr] = 0.f;
    float m_r[2] = {-INFINITY, -INFINITY};
    float l_r[2] = {0.f, 0.f};

    for (int kbi = 0; kbi < NSEQ / 64; ++kbi) {
        const int cur = kbi & 1;
        // prefetch tile t+1 into registers
        u16x8 nk0, nk1, nv0, nv1;
        const bool pre = (kbi + 1 < NSEQ / 64);
        if (pre) {
            const unsigned short* nkp = kgp + (size_t)(kbi + 1) * 64 * DHEAD;
            const unsigned short* nvp = vgp + (size_t)(kbi + 1) * 64;
            nk0 = *reinterpret_cast<const u16x8*>(nkp);
            nk1 = *reinterpret_cast<const u16x8*>(nkp + 8);
            nv0 = *reinterpret_cast<const u16x8*>(nvp);
            nv1 = *reinterpret_cast<const u16x8*>(nvp + 8);
        }

        // S^T[j][q] = K[j][:]·Q[q][:] for both q-halves; kf read once per jt
        f32x4 sacc[2][4];
#pragma unroll
        for (int qh = 0; qh < 2; ++qh)
#pragma unroll
            for (int jt = 0; jt < 4; ++jt)
#pragma unroll
                for (int rr = 0; rr < 4; ++rr) sacc[qh][jt][rr] = 0.f;
        __builtin_amdgcn_s_setprio(1);
#pragma unroll
        for (int jt = 0; jt < 4; ++jt) {
            const int row = jt * 16 + ql;
            bf16x8 kf0 = *reinterpret_cast<const bf16x8*>(&Ks[cur][row * 64 + SWC(row, g * 8)]);
            bf16x8 kf1 = *reinterpret_cast<const bf16x8*>(&Ks[cur][row * 64 + SWC(row, 32 + g * 8)]);
            sacc[0][jt] = __builtin_amdgcn_mfma_f32_16x16x32_bf16(kf0, qf[0][0], sacc[0][jt], 0, 0, 0);
            sacc[0][jt] = __builtin_amdgcn_mfma_f32_16x16x32_bf16(kf1, qf[0][1], sacc[0][jt], 0, 0, 0);
            sacc[1][jt] = __builtin_amdgcn_mfma_f32_16x16x32_bf16(kf0, qf[1][0], sacc[1][jt], 0, 0, 0);
            sacc[1][jt] = __builtin_amdgcn_mfma_f32_16x16x32_bf16(kf1, qf[1][1], sacc[1][jt], 0, 0, 0);
        }
        __builtin_amdgcn_s_setprio(0);

        // per-half online softmax with defer-max; write P^T rows
#pragma unroll
        for (int qh = 0; qh < 2; ++qh) {
            float sv[16];
#pragma unroll
            for (int jt = 0; jt < 4; ++jt)
#pragma unroll
                for (int rr = 0; rr < 4; ++rr) sv[jt * 4 + rr] = sacc[qh][jt][rr];
            // max tree (v_max3-friendly groupings)
            float a0 = fmaxf(fmaxf(sv[0], sv[1]), sv[2]);
            float a1 = fmaxf(fmaxf(sv[3], sv[4]), sv[5]);
            float a2 = fmaxf(fmaxf(sv[6], sv[7]), sv[8]);
            float a3 = fmaxf(fmaxf(sv[9], sv[10]), sv[11]);
            float a4 = fmaxf(fmaxf(sv[12], sv[13]), sv[14]);
            float mx = fmaxf(fmaxf(fmaxf(a0, a1), a2), fmaxf(fmaxf(a3, a4), sv[15]));
            mx = fmaxf(mx, __shfl_xor(mx, 16));
            mx = fmaxf(mx, __shfl_xor(mx, 32));
            if (__any(mx > m_r[qh] + 8.f)) {
                const float m_new = fmaxf(m_r[qh], mx);
                const float alpha = fexp2(m_r[qh] - m_new);
                l_r[qh] *= alpha;
#pragma unroll
                for (int dt = 0; dt < 4; ++dt)
#pragma unroll
                    for (int rr = 0; rr < 4; ++rr) acc_o[qh][dt][rr] *= alpha;
                m_r[qh] = m_new;
            }
            float p[16];
#pragma unroll
            for (int i = 0; i < 16; ++i) p[i] = fexp2(sv[i] - m_r[qh]);
            float s0 = (p[0] + p[1]) + (p[2] + p[3]);
            float s1 = (p[4] + p[5]) + (p[6] + p[7]);
            float s2 = (p[8] + p[9]) + (p[10] + p[11]);
            float s3 = (p[12] + p[13]) + (p[14] + p[15]);
            float ps = (s0 + s1) + (s2 + s3);
            ps += __shfl_xor(ps, 16);
            ps += __shfl_xor(ps, 32);
            l_r[qh] += ps;

            const int prow = w * 32 + qh * 16 + ql;
#pragma unroll
            for (int jt = 0; jt < 4; ++jt) {
                uint2 u;
                u.x = cvtpk(p[jt * 4 + 0], p[jt * 4 + 1]);
                u.y = cvtpk(p[jt * 4 + 2], p[jt * 4 + 3]);
                *reinterpret_cast<uint2*>(&Ps[prow * 64 + SWC(prow, jt * 16 + g * 4)]) = u;
            }
        }

        // O^T[d][q] += Vt[d][:]·P^T[:][q]; vf read once per (js,dt), reused
        __builtin_amdgcn_s_setprio(1);
#pragma unroll
        for (int js = 0; js < 2; ++js) {
            bf16x8 vf[4];
#pragma unroll
            for (int dt = 0; dt < 4; ++dt) {
                const int row = dt * 16 + ql;
                vf[dt] = *reinterpret_cast<const bf16x8*>(&Vts[cur][row * 64 + SWC(row, js * 32 + g * 8)]);
            }
#pragma unroll
            for (int qh = 0; qh < 2; ++qh) {
                const int prow = w * 32 + qh * 16 + ql;
                bf16x8 pf = *reinterpret_cast<const bf16x8*>(&Ps[prow * 64 + SWC(prow, js * 32 + g * 8)]);
#pragma unroll
                for (int dt = 0; dt < 4; ++dt)
                    acc_o[qh][dt] = __builtin_amdgcn_mfma_f32_16x16x32_bf16(vf[dt], pf, acc_o[qh][dt], 0, 0, 0);
            }
        }
        __builtin_amdgcn_s_setprio(0);

        // stage tile t+1 into the alternate buffer
        if (pre) {
            *reinterpret_cast<u16x8*>(&Ks [cur ^ 1][st0]) = nk0;
            *reinterpret_cast<u16x8*>(&Ks [cur ^ 1][st1]) = nk1;
            *reinterpret_cast<u16x8*>(&Vts[cur ^ 1][st0]) = nv0;
            *reinterpret_cast<u16x8*>(&Vts[cur ^ 1][st1]) = nv1;
        }
        __syncthreads();
    }

    // epilogue: O[b][n][h*64+d], n = qblk*128 + w*32 + qh*16 + ql
#pragma unroll
    for (int qh = 0; qh < 2; ++qh) {
        const float rinv = 1.0f / l_r[qh];
        const int n = qblk * 128 + w * 32 + qh * 16 + ql;
        unsigned short* dst = og + ((size_t)b * NSEQ + n) * INNER + h * DHEAD;
#pragma unroll
        for (int dt = 0; dt < 4; ++dt) {
            uint2 u;
            u.x = cvtpk(acc_o[qh][dt][0] * rinv, acc_o[qh][dt][1] * rinv);
            u.y = cvtpk(acc_o[qh][dt][2] * rinv, acc_o[qh][dt][3] * rinv);
            *reinterpret_cast<uint2*>(&dst[dt * 16 + g * 4]) = u;
        }
    }
}

// ---------------------------------------------------------------------------

extern "C" void kernel_launch(void* const* d_in, const int* in_sizes, int n_in,
                              void* d_out, int out_size, void* d_ws, size_t ws_size,
                              hipStream_t stream) {
    const float* x     = (const float*)d_in[0];
    const float* w_qkv = (const float*)d_in[1];
    const float* w_out = (const float*)d_in[2];
    const float* b_out = (const float*)d_in[3];
    float* out = (float*)d_out;

    unsigned short* ws = (unsigned short*)d_ws;
    const size_t nX  = (size_t)MTOT * DIM;
    const size_t nWq = (size_t)DIM * 3 * INNER;
    const size_t nWo = (size_t)DIM * INNER;
    unsigned short* Xb  = ws;
    unsigned short* Wqt = Xb  + nX;
    unsigned short* Wot = Wqt + nWq;
    unsigned short* qb  = Wot + nWo;
    unsigned short* kb  = qb  + nX;
    unsigned short* vt  = kb  + nX;
    unsigned short* Ob  = vt  + nX;

    cvt_bf16<<<dim3(nX / 8 / 256), dim3(256), 0, stream>>>(x, Xb);
    transp_bf16<<<dim3(3 * INNER / 32, DIM / 32), dim3(256), 0, stream>>>(w_qkv, Wqt, DIM, 3 * INNER);
    transp_bf16<<<dim3(DIM / 32, INNER / 32), dim3(256), 0, stream>>>(w_out, Wot, INNER, DIM);

    gemm_qkv_mfma<<<dim3(3 * INNER / 128, MTOT / 128), dim3(256), 0, stream>>>(Xb, Wqt, qb, kb, vt);
    attn_mfma<<<dim3(BATCH * HEADS, NSEQ / 128), dim3(256), 0, stream>>>(qb, kb, vt, Ob);
    gemm_out_mfma<<<dim3(DIM / 128, MTOT / 128), dim3(256), 0, stream>>>(Ob, Wot, b_out, out);
}

// Round 7
// 227.564 us; speedup vs baseline: 19.6435x; 1.0309x over previous
//
#include <hip/hip_runtime.h>
#include <math.h>

#define BATCH   4
#define NSEQ    2048
#define DIM     1024
#define HEADS   16
#define DHEAD   64
#define INNER   1024
#define MTOT    (BATCH*NSEQ)     // 8192
// softmax in log2 domain: SCALE * log2(e), folded into Q at QKV epilogue
#define SC_L2E  0.04508422f

typedef __attribute__((ext_vector_type(8))) unsigned short u16x8;
typedef __attribute__((ext_vector_type(4))) unsigned short u16x4;
typedef __attribute__((ext_vector_type(8))) short          bf16x8;
typedef __attribute__((ext_vector_type(4))) float          f32x4;

__device__ __forceinline__ unsigned short f2bf(float f) {
    unsigned int u = __builtin_bit_cast(unsigned int, f);
    u += 0x7FFFu + ((u >> 16) & 1u);       // RNE
    return (unsigned short)(u >> 16);
}

__device__ __forceinline__ float fexp2(float x) {
    float r; asm("v_exp_f32 %0, %1" : "=v"(r) : "v"(x)); return r;
}

__device__ __forceinline__ unsigned int cvtpk(float lo, float hi) {
    unsigned int r; asm("v_cvt_pk_bf16_f32 %0, %1, %2" : "=v"(r) : "v"(lo), "v"(hi));
    return r;
}

// async global->LDS, 16B per lane; lds base must be wave-uniform
#define GLDS16(gp, lp) __builtin_amdgcn_global_load_lds( \
    (const __attribute__((address_space(1))) unsigned int*)(gp), \
    (__attribute__((address_space(3))) unsigned int*)(lp), 16, 0, 0)

// XOR swizzle: ushort column c (0..63) within row r -> permute 16B slots.
#define SWC(r, c) ((c) ^ (((r) & 7) << 3))

// ---------------------------------------------------------------------------
// fp32 -> bf16 elementwise convert (x)
// ---------------------------------------------------------------------------
__global__ __launch_bounds__(256) void cvt_bf16(const float* __restrict__ in,
                                                unsigned short* __restrict__ out)
{
    const int i = blockIdx.x * 256 + threadIdx.x;
    const float4* p = reinterpret_cast<const float4*>(in) + (size_t)i * 2;
    float4 a = p[0], b = p[1];
    u16x8 o;
    o[0]=f2bf(a.x); o[1]=f2bf(a.y); o[2]=f2bf(a.z); o[3]=f2bf(a.w);
    o[4]=f2bf(b.x); o[5]=f2bf(b.y); o[6]=f2bf(b.z); o[7]=f2bf(b.w);
    reinterpret_cast<u16x8*>(out)[i] = o;
}

// ---------------------------------------------------------------------------
// fp32 [R][C] -> bf16 [C][R] transpose (weights)
// ---------------------------------------------------------------------------
__global__ __launch_bounds__(256) void transp_bf16(const float* __restrict__ in,
                                                   unsigned short* __restrict__ out,
                                                   int R, int C)
{
    __shared__ float tile[32][33];
    const int c0 = blockIdx.x * 32, r0 = blockIdx.y * 32;
    const int tx = threadIdx.x & 31, ty = threadIdx.x >> 5;
#pragma unroll
    for (int i = 0; i < 32; i += 8)
        tile[ty + i][tx] = in[(size_t)(r0 + ty + i) * C + c0 + tx];
    __syncthreads();
#pragma unroll
    for (int i = 0; i < 32; i += 8)
        out[(size_t)(c0 + ty + i) * R + r0 + tx] = f2bf(tile[tx][ty + i]);
}

// ---------------------------------------------------------------------------
// bf16 MFMA GEMM, 128x128 tile, BK=32, 4 waves, global_load_lds staging.
// ---------------------------------------------------------------------------

// QKV: N=3072. Epilogue scatters q (pre-scaled by SC_L2E), k -> [b,h,n,d],
// v -> vt[b,h,d,n'] where n' permutes keys within each 64-block:
// key bits [k5 k4 k3 k2 k1 k0] -> col [k5 k3 k2 k4 k1 k0]. This makes the
// attn PV step consume P directly from each lane's S^T output registers.
__global__ __launch_bounds__(256) void gemm_qkv_mfma(const unsigned short* __restrict__ A,
                                                     const unsigned short* __restrict__ Bt,
                                                     unsigned short* __restrict__ qb,
                                                     unsigned short* __restrict__ kb,
                                                     unsigned short* __restrict__ vt)
{
    __shared__ unsigned short As[128][32];
    __shared__ unsigned short Bs[128][32];

    const int t = threadIdx.x;
    const int l = t & 63, w = t >> 6;
    const int wr = w >> 1, wc = w & 1;
    const int g = l >> 4, ql = l & 15;
    const int row0 = blockIdx.y * 128;
    const int col0 = blockIdx.x * 128;
    const int lr = l >> 2, lc = l & 3;     // staging lane mapping

    f32x4 acc[4][4];
#pragma unroll
    for (int mi = 0; mi < 4; ++mi)
#pragma unroll
        for (int ni = 0; ni < 4; ++ni)
#pragma unroll
            for (int r = 0; r < 4; ++r) acc[mi][ni][r] = 0.f;

    for (int k0 = 0; k0 < DIM; k0 += 32) {
        __syncthreads();
        {
            const unsigned short* ag = A  + (size_t)(row0 + 32 * w + lr) * DIM + k0 + lc * 8;
            const unsigned short* bg = Bt + (size_t)(col0 + 32 * w + lr) * DIM + k0 + lc * 8;
            GLDS16(ag,              &As[32 * w][0]);
            GLDS16(ag + 16 * DIM,   &As[32 * w + 16][0]);
            GLDS16(bg,              &Bs[32 * w][0]);
            GLDS16(bg + 16 * DIM,   &Bs[32 * w + 16][0]);
        }
        __syncthreads();

        bf16x8 af[4], bf[4];
#pragma unroll
        for (int mi = 0; mi < 4; ++mi)
            af[mi] = *reinterpret_cast<const bf16x8*>(&As[wr * 64 + mi * 16 + ql][g * 8]);
#pragma unroll
        for (int ni = 0; ni < 4; ++ni)
            bf[ni] = *reinterpret_cast<const bf16x8*>(&Bs[wc * 64 + ni * 16 + ql][g * 8]);
#pragma unroll
        for (int mi = 0; mi < 4; ++mi)
#pragma unroll
            for (int ni = 0; ni < 4; ++ni)
                acc[mi][ni] = __builtin_amdgcn_mfma_f32_16x16x32_bf16(af[mi], bf[ni], acc[mi][ni], 0, 0, 0);
    }

#pragma unroll
    for (int mi = 0; mi < 4; ++mi) {
        const int m0 = row0 + wr * 64 + mi * 16 + g * 4;
        const int b  = m0 >> 11, n0 = m0 & 2047;
#pragma unroll
        for (int ni = 0; ni < 4; ++ni) {
            const int c = col0 + wc * 64 + ni * 16 + ql;
            const int part = c >> 10, inner = c & 1023;
            const int h = inner >> 6, d = inner & 63;
            if (part == 2) {
                // permuted V store: col = [k5 k3 k2 k4 k1 k0] of key (n0&63).
                // k5,k1,k0 pass through; n0 is 4-aligned so the u16x4 store
                // (keys n0..n0+3, bits k1k0) stays contiguous.
                const int key0 = n0 & 63;
                const int nst  = (n0 & ~63)
                               | (key0 & 0x23)                 // k5, k1, k0
                               | (((key0 >> 3) & 1) << 4)      // k3 -> bit4
                               | (((key0 >> 2) & 1) << 3)      // k2 -> bit3
                               | (((key0 >> 4) & 1) << 2);     // k4 -> bit2
                u16x4 pk;
#pragma unroll
                for (int r = 0; r < 4; ++r) pk[r] = f2bf(acc[mi][ni][r]);
                *reinterpret_cast<u16x4*>(&vt[(((size_t)b * HEADS + h) * DHEAD + d) * NSEQ + nst]) = pk;
            } else if (part == 0) {
                unsigned short* dst = qb + (((size_t)b * HEADS + h) * NSEQ + n0) * DHEAD + d;
#pragma unroll
                for (int r = 0; r < 4; ++r) dst[(size_t)r * DHEAD] = f2bf(acc[mi][ni][r] * SC_L2E);
            } else {
                unsigned short* dst = kb + (((size_t)b * HEADS + h) * NSEQ + n0) * DHEAD + d;
#pragma unroll
                for (int r = 0; r < 4; ++r) dst[(size_t)r * DHEAD] = f2bf(acc[mi][ni][r]);
            }
        }
    }
}

// out-proj: N=1024, + bias, fp32 out
__global__ __launch_bounds__(256) void gemm_out_mfma(const unsigned short* __restrict__ A,
                                                     const unsigned short* __restrict__ Bt,
                                                     const float* __restrict__ bias,
                                                     float* __restrict__ out)
{
    __shared__ unsigned short As[128][32];
    __shared__ unsigned short Bs[128][32];

    const int t = threadIdx.x;
    const int l = t & 63, w = t >> 6;
    const int wr = w >> 1, wc = w & 1;
    const int g = l >> 4, ql = l & 15;
    const int row0 = blockIdx.y * 128;
    const int col0 = blockIdx.x * 128;
    const int lr = l >> 2, lc = l & 3;

    f32x4 acc[4][4];
#pragma unroll
    for (int mi = 0; mi < 4; ++mi)
#pragma unroll
        for (int ni = 0; ni < 4; ++ni)
#pragma unroll
            for (int r = 0; r < 4; ++r) acc[mi][ni][r] = 0.f;

    for (int k0 = 0; k0 < INNER; k0 += 32) {
        __syncthreads();
        {
            const unsigned short* ag = A  + (size_t)(row0 + 32 * w + lr) * INNER + k0 + lc * 8;
            const unsigned short* bg = Bt + (size_t)(col0 + 32 * w + lr) * INNER + k0 + lc * 8;
            GLDS16(ag,               &As[32 * w][0]);
            GLDS16(ag + 16 * INNER,  &As[32 * w + 16][0]);
            GLDS16(bg,               &Bs[32 * w][0]);
            GLDS16(bg + 16 * INNER,  &Bs[32 * w + 16][0]);
        }
        __syncthreads();

        bf16x8 af[4], bf[4];
#pragma unroll
        for (int mi = 0; mi < 4; ++mi)
            af[mi] = *reinterpret_cast<const bf16x8*>(&As[wr * 64 + mi * 16 + ql][g * 8]);
#pragma unroll
        for (int ni = 0; ni < 4; ++ni)
            bf[ni] = *reinterpret_cast<const bf16x8*>(&Bs[wc * 64 + ni * 16 + ql][g * 8]);
#pragma unroll
        for (int mi = 0; mi < 4; ++mi)
#pragma unroll
            for (int ni = 0; ni < 4; ++ni)
                acc[mi][ni] = __builtin_amdgcn_mfma_f32_16x16x32_bf16(af[mi], bf[ni], acc[mi][ni], 0, 0, 0);
    }

#pragma unroll
    for (int mi = 0; mi < 4; ++mi) {
        const int m0 = row0 + wr * 64 + mi * 16 + g * 4;
#pragma unroll
        for (int ni = 0; ni < 4; ++ni) {
            const int c = col0 + wc * 64 + ni * 16 + ql;
            const float bv = bias[c];
#pragma unroll
            for (int r = 0; r < 4; ++r)
                out[(size_t)(m0 + r) * DIM + c] = acc[mi][ni][r] + bv;
        }
    }
}

// ---------------------------------------------------------------------------
// MFMA flash attention, swapped operands: S^T = K·Q^T, O^T = V^T·P^T.
// Wq=32, QBLK=128, 4 waves, grid (64,16). V columns are pre-permuted in
// global memory so each lane's S^T output registers ARE the PV B-operand:
// P never touches LDS. LDS = K/V double-buffer only (32KB -> 5 blocks/CU).
// ---------------------------------------------------------------------------
__global__ __launch_bounds__(256) void attn_mfma(const unsigned short* __restrict__ qg,
                                                 const unsigned short* __restrict__ kg,
                                                 const unsigned short* __restrict__ vtg,
                                                 unsigned short* __restrict__ og)
{
    __shared__ unsigned short Ks [2][64 * 64];
    __shared__ unsigned short Vts[2][64 * 64];   // [d][j'] (permuted key cols)

    const int bh = blockIdx.x;
    const int b = bh >> 4, h = bh & 15;
    const int qblk = blockIdx.y;
    const int t = threadIdx.x, l = t & 63, w = t >> 6;
    const int g = l >> 4, ql = l & 15;

    const size_t hb = (size_t)bh * NSEQ * DHEAD;

    // Q fragments for both q-halves (pre-scaled by SC_L2E)
    bf16x8 qf[2][2];
#pragma unroll
    for (int qh = 0; qh < 2; ++qh) {
        const unsigned short* qrow = qg + hb + (size_t)(qblk * 128 + w * 32 + qh * 16 + ql) * DHEAD;
        qf[qh][0] = *reinterpret_cast<const bf16x8*>(qrow + g * 8);
        qf[qh][1] = *reinterpret_cast<const bf16x8*>(qrow + 32 + g * 8);
    }

    // staging lane mapping: row r, two 16B chunks at cols seg*16, seg*16+8
    const int r = t >> 2, seg = t & 3;
    const unsigned short* kgp = kg  + hb + (size_t)r * DHEAD + seg * 16;
    const unsigned short* vgp = vtg + hb + (size_t)r * NSEQ  + seg * 16;
    const int st0 = r * 64 + SWC(r, seg * 16);
    const int st1 = r * 64 + SWC(r, seg * 16 + 8);

    // prologue: stage tile 0 into buffer 0
    {
        u16x8 k0 = *reinterpret_cast<const u16x8*>(kgp);
        u16x8 k1 = *reinterpret_cast<const u16x8*>(kgp + 8);
        u16x8 v0 = *reinterpret_cast<const u16x8*>(vgp);
        u16x8 v1 = *reinterpret_cast<const u16x8*>(vgp + 8);
        *reinterpret_cast<u16x8*>(&Ks [0][st0]) = k0;
        *reinterpret_cast<u16x8*>(&Ks [0][st1]) = k1;
        *reinterpret_cast<u16x8*>(&Vts[0][st0]) = v0;
        *reinterpret_cast<u16x8*>(&Vts[0][st1]) = v1;
    }
    __syncthreads();

    f32x4 acc_o[2][4];
#pragma unroll
    for (int qh = 0; qh < 2; ++qh)
#pragma unroll
        for (int dt = 0; dt < 4; ++dt)
#pragma unroll
            for (int rr = 0; rr < 4; ++rr) acc_o[qh][dt][rr] = 0.f;
    float m_r[2] = {-INFINITY, -INFINITY};
    float l_r[2] = {0.f, 0.f};

    for (int kbi = 0; kbi < NSEQ / 64; ++kbi) {
        const int cur = kbi & 1;
        // prefetch tile t+1 into registers
        u16x8 nk0, nk1, nv0, nv1;
        const bool pre = (kbi + 1 < NSEQ / 64);
        if (pre) {
            const unsigned short* nkp = kgp + (size_t)(kbi + 1) * 64 * DHEAD;
            const unsigned short* nvp = vgp + (size_t)(kbi + 1) * 64;
            nk0 = *reinterpret_cast<const u16x8*>(nkp);
            nk1 = *reinterpret_cast<const u16x8*>(nkp + 8);
            nv0 = *reinterpret_cast<const u16x8*>(nvp);
            nv1 = *reinterpret_cast<const u16x8*>(nvp + 8);
        }

        // S^T[j][q] = K[j][:]·Q[q][:] for both q-halves; kf read once per jt
        f32x4 sacc[2][4];
#pragma unroll
        for (int qh = 0; qh < 2; ++qh)
#pragma unroll
            for (int jt = 0; jt < 4; ++jt)
#pragma unroll
                for (int rr = 0; rr < 4; ++rr) sacc[qh][jt][rr] = 0.f;
        __builtin_amdgcn_s_setprio(1);
#pragma unroll
        for (int jt = 0; jt < 4; ++jt) {
            const int row = jt * 16 + ql;
            bf16x8 kf0 = *reinterpret_cast<const bf16x8*>(&Ks[cur][row * 64 + SWC(row, g * 8)]);
            bf16x8 kf1 = *reinterpret_cast<const bf16x8*>(&Ks[cur][row * 64 + SWC(row, 32 + g * 8)]);
            sacc[0][jt] = __builtin_amdgcn_mfma_f32_16x16x32_bf16(kf0, qf[0][0], sacc[0][jt], 0, 0, 0);
            sacc[0][jt] = __builtin_amdgcn_mfma_f32_16x16x32_bf16(kf1, qf[0][1], sacc[0][jt], 0, 0, 0);
            sacc[1][jt] = __builtin_amdgcn_mfma_f32_16x16x32_bf16(kf0, qf[1][0], sacc[1][jt], 0, 0, 0);
            sacc[1][jt] = __builtin_amdgcn_mfma_f32_16x16x32_bf16(kf1, qf[1][1], sacc[1][jt], 0, 0, 0);
        }
        __builtin_amdgcn_s_setprio(0);

        // per-half online softmax with defer-max; pack P into registers
        bf16x8 pf[2][2];     // [qh][js] -> PV B-operand, direct from regs
#pragma unroll
        for (int qh = 0; qh < 2; ++qh) {
            float sv[16];
#pragma unroll
            for (int jt = 0; jt < 4; ++jt)
#pragma unroll
                for (int rr = 0; rr < 4; ++rr) sv[jt * 4 + rr] = sacc[qh][jt][rr];
            float a0 = fmaxf(fmaxf(sv[0], sv[1]), sv[2]);
            float a1 = fmaxf(fmaxf(sv[3], sv[4]), sv[5]);
            float a2 = fmaxf(fmaxf(sv[6], sv[7]), sv[8]);
            float a3 = fmaxf(fmaxf(sv[9], sv[10]), sv[11]);
            float a4 = fmaxf(fmaxf(sv[12], sv[13]), sv[14]);
            float mx = fmaxf(fmaxf(fmaxf(a0, a1), a2), fmaxf(fmaxf(a3, a4), sv[15]));
            mx = fmaxf(mx, __shfl_xor(mx, 16));
            mx = fmaxf(mx, __shfl_xor(mx, 32));
            if (__any(mx > m_r[qh] + 8.f)) {
                const float m_new = fmaxf(m_r[qh], mx);
                const float alpha = fexp2(m_r[qh] - m_new);
                l_r[qh] *= alpha;
#pragma unroll
                for (int dt = 0; dt < 4; ++dt)
#pragma unroll
                    for (int rr = 0; rr < 4; ++rr) acc_o[qh][dt][rr] *= alpha;
                m_r[qh] = m_new;
            }
            float p[16];
#pragma unroll
            for (int i = 0; i < 16; ++i) p[i] = fexp2(sv[i] - m_r[qh]);
            float s0 = (p[0] + p[1]) + (p[2] + p[3]);
            float s1 = (p[4] + p[5]) + (p[6] + p[7]);
            float s2 = (p[8] + p[9]) + (p[10] + p[11]);
            float s3 = (p[12] + p[13]) + (p[14] + p[15]);
            float ps = (s0 + s1) + (s2 + s3);
            ps += __shfl_xor(ps, 16);
            ps += __shfl_xor(ps, 32);
            l_r[qh] += ps;

            // pack: pf[qh][js] covers p[8*js .. 8*js+7]; V's global column
            // permutation makes this the correct key order for PV.
#pragma unroll
            for (int js = 0; js < 2; ++js) {
                unsigned int u0 = cvtpk(p[8 * js + 0], p[8 * js + 1]);
                unsigned int u1 = cvtpk(p[8 * js + 2], p[8 * js + 3]);
                unsigned int u2 = cvtpk(p[8 * js + 4], p[8 * js + 5]);
                unsigned int u3 = cvtpk(p[8 * js + 6], p[8 * js + 7]);
                uint4 uu = {u0, u1, u2, u3};
                pf[qh][js] = __builtin_bit_cast(bf16x8, uu);
            }
        }

        // O^T[d][q] += Vt[d][:]·P^T[:][q]; vf read once per (js,dt)
        __builtin_amdgcn_s_setprio(1);
#pragma unroll
        for (int js = 0; js < 2; ++js) {
            bf16x8 vf[4];
#pragma unroll
            for (int dt = 0; dt < 4; ++dt) {
                const int row = dt * 16 + ql;
                vf[dt] = *reinterpret_cast<const bf16x8*>(&Vts[cur][row * 64 + SWC(row, js * 32 + g * 8)]);
            }
#pragma unroll
            for (int qh = 0; qh < 2; ++qh)
#pragma unroll
                for (int dt = 0; dt < 4; ++dt)
                    acc_o[qh][dt] = __builtin_amdgcn_mfma_f32_16x16x32_bf16(vf[dt], pf[qh][js], acc_o[qh][dt], 0, 0, 0);
        }
        __builtin_amdgcn_s_setprio(0);

        // stage tile t+1 into the alternate buffer
        if (pre) {
            *reinterpret_cast<u16x8*>(&Ks [cur ^ 1][st0]) = nk0;
            *reinterpret_cast<u16x8*>(&Ks [cur ^ 1][st1]) = nk1;
            *reinterpret_cast<u16x8*>(&Vts[cur ^ 1][st0]) = nv0;
            *reinterpret_cast<u16x8*>(&Vts[cur ^ 1][st1]) = nv1;
        }
        __syncthreads();
    }

    // epilogue: O[b][n][h*64+d], n = qblk*128 + w*32 + qh*16 + ql
#pragma unroll
    for (int qh = 0; qh < 2; ++qh) {
        const float rinv = 1.0f / l_r[qh];
        const int n = qblk * 128 + w * 32 + qh * 16 + ql;
        unsigned short* dst = og + ((size_t)b * NSEQ + n) * INNER + h * DHEAD;
#pragma unroll
        for (int dt = 0; dt < 4; ++dt) {
            uint2 u;
            u.x = cvtpk(acc_o[qh][dt][0] * rinv, acc_o[qh][dt][1] * rinv);
            u.y = cvtpk(acc_o[qh][dt][2] * rinv, acc_o[qh][dt][3] * rinv);
            *reinterpret_cast<uint2*>(&dst[dt * 16 + g * 4]) = u;
        }
    }
}

// ---------------------------------------------------------------------------

extern "C" void kernel_launch(void* const* d_in, const int* in_sizes, int n_in,
                              void* d_out, int out_size, void* d_ws, size_t ws_size,
                              hipStream_t stream) {
    const float* x     = (const float*)d_in[0];
    const float* w_qkv = (const float*)d_in[1];
    const float* w_out = (const float*)d_in[2];
    const float* b_out = (const float*)d_in[3];
    float* out = (float*)d_out;

    unsigned short* ws = (unsigned short*)d_ws;
    const size_t nX  = (size_t)MTOT * DIM;
    const size_t nWq = (size_t)DIM * 3 * INNER;
    const size_t nWo = (size_t)DIM * INNER;
    unsigned short* Xb  = ws;
    unsigned short* Wqt = Xb  + nX;
    unsigned short* Wot = Wqt + nWq;
    unsigned short* qb  = Wot + nWo;
    unsigned short* kb  = qb  + nX;
    unsigned short* vt  = kb  + nX;
    unsigned short* Ob  = vt  + nX;

    cvt_bf16<<<dim3(nX / 8 / 256), dim3(256), 0, stream>>>(x, Xb);
    transp_bf16<<<dim3(3 * INNER / 32, DIM / 32), dim3(256), 0, stream>>>(w_qkv, Wqt, DIM, 3 * INNER);
    transp_bf16<<<dim3(DIM / 32, INNER / 32), dim3(256), 0, stream>>>(w_out, Wot, INNER, DIM);

    gemm_qkv_mfma<<<dim3(3 * INNER / 128, MTOT / 128), dim3(256), 0, stream>>>(Xb, Wqt, qb, kb, vt);
    attn_mfma<<<dim3(BATCH * HEADS, NSEQ / 128), dim3(256), 0, stream>>>(qb, kb, vt, Ob);
    gemm_out_mfma<<<dim3(DIM / 128, MTOT / 128), dim3(256), 0, stream>>>(Ob, Wot, b_out, out);
}

// Round 8
// 211.489 us; speedup vs baseline: 21.1366x; 1.0760x over previous
//
#include <hip/hip_runtime.h>
#include <math.h>

#define BATCH   4
#define NSEQ    2048
#define DIM     1024
#define HEADS   16
#define DHEAD   64
#define INNER   1024
#define MTOT    (BATCH*NSEQ)     // 8192
// softmax in log2 domain: SCALE * log2(e), folded into Q at QKV epilogue
#define SC_L2E  0.04508422f

typedef __attribute__((ext_vector_type(8))) unsigned short u16x8;
typedef __attribute__((ext_vector_type(4))) unsigned short u16x4;
typedef __attribute__((ext_vector_type(8))) short          bf16x8;
typedef __attribute__((ext_vector_type(4))) float          f32x4;

__device__ __forceinline__ unsigned short f2bf(float f) {
    unsigned int u = __builtin_bit_cast(unsigned int, f);
    u += 0x7FFFu + ((u >> 16) & 1u);       // RNE
    return (unsigned short)(u >> 16);
}

__device__ __forceinline__ float fexp2(float x) {
    float r; asm("v_exp_f32 %0, %1" : "=v"(r) : "v"(x)); return r;
}

__device__ __forceinline__ unsigned int cvtpk(float lo, float hi) {
    unsigned int r; asm("v_cvt_pk_bf16_f32 %0, %1, %2" : "=v"(r) : "v"(lo), "v"(hi));
    return r;
}

// async global->LDS, 16B per lane; lds base must be wave-uniform
#define GLDS16(gp, lp) __builtin_amdgcn_global_load_lds( \
    (const __attribute__((address_space(1))) unsigned int*)(gp), \
    (__attribute__((address_space(3))) unsigned int*)(lp), 16, 0, 0)

// XOR swizzle: ushort column c (0..63) within row r -> permute 16B slots.
#define SWC(r, c) ((c) ^ (((r) & 7) << 3))

// ---------------------------------------------------------------------------
// fp32 -> bf16 elementwise convert (x)
// ---------------------------------------------------------------------------
__global__ __launch_bounds__(256) void cvt_bf16(const float* __restrict__ in,
                                                unsigned short* __restrict__ out)
{
    const int i = blockIdx.x * 256 + threadIdx.x;
    const float4* p = reinterpret_cast<const float4*>(in) + (size_t)i * 2;
    float4 a = p[0], b = p[1];
    u16x8 o;
    o[0]=f2bf(a.x); o[1]=f2bf(a.y); o[2]=f2bf(a.z); o[3]=f2bf(a.w);
    o[4]=f2bf(b.x); o[5]=f2bf(b.y); o[6]=f2bf(b.z); o[7]=f2bf(b.w);
    reinterpret_cast<u16x8*>(out)[i] = o;
}

// ---------------------------------------------------------------------------
// fp32 [R][C] -> bf16 [C][R] transpose (weights)
// ---------------------------------------------------------------------------
__global__ __launch_bounds__(256) void transp_bf16(const float* __restrict__ in,
                                                   unsigned short* __restrict__ out,
                                                   int R, int C)
{
    __shared__ float tile[32][33];
    const int c0 = blockIdx.x * 32, r0 = blockIdx.y * 32;
    const int tx = threadIdx.x & 31, ty = threadIdx.x >> 5;
#pragma unroll
    for (int i = 0; i < 32; i += 8)
        tile[ty + i][tx] = in[(size_t)(r0 + ty + i) * C + c0 + tx];
    __syncthreads();
#pragma unroll
    for (int i = 0; i < 32; i += 8)
        out[(size_t)(c0 + ty + i) * R + r0 + tx] = f2bf(tile[tx][ty + i]);
}

// ---------------------------------------------------------------------------
// bf16 MFMA GEMM, 128x128 tile, BK=32, 4 waves, global_load_lds staging.
// ---------------------------------------------------------------------------

// QKV: N=3072. Epilogue scatters q (pre-scaled by SC_L2E), k -> [b,h,n,d],
// v -> vt[b,h,d,n'] where n' permutes keys within each 64-block:
// key bits [k5 k4 k3 k2 k1 k0] -> col [k5 k3 k2 k4 k1 k0]. This makes the
// attn PV step consume P directly from each lane's S^T output registers.
__global__ __launch_bounds__(256) void gemm_qkv_mfma(const unsigned short* __restrict__ A,
                                                     const unsigned short* __restrict__ Bt,
                                                     unsigned short* __restrict__ qb,
                                                     unsigned short* __restrict__ kb,
                                                     unsigned short* __restrict__ vt)
{
    __shared__ unsigned short As[128][32];
    __shared__ unsigned short Bs[128][32];

    const int t = threadIdx.x;
    const int l = t & 63, w = t >> 6;
    const int wr = w >> 1, wc = w & 1;
    const int g = l >> 4, ql = l & 15;
    const int row0 = blockIdx.y * 128;
    const int col0 = blockIdx.x * 128;
    const int lr = l >> 2, lc = l & 3;     // staging lane mapping

    f32x4 acc[4][4];
#pragma unroll
    for (int mi = 0; mi < 4; ++mi)
#pragma unroll
        for (int ni = 0; ni < 4; ++ni)
#pragma unroll
            for (int r = 0; r < 4; ++r) acc[mi][ni][r] = 0.f;

    for (int k0 = 0; k0 < DIM; k0 += 32) {
        __syncthreads();
        {
            const unsigned short* ag = A  + (size_t)(row0 + 32 * w + lr) * DIM + k0 + lc * 8;
            const unsigned short* bg = Bt + (size_t)(col0 + 32 * w + lr) * DIM + k0 + lc * 8;
            GLDS16(ag,              &As[32 * w][0]);
            GLDS16(ag + 16 * DIM,   &As[32 * w + 16][0]);
            GLDS16(bg,              &Bs[32 * w][0]);
            GLDS16(bg + 16 * DIM,   &Bs[32 * w + 16][0]);
        }
        __syncthreads();

        bf16x8 af[4], bf[4];
#pragma unroll
        for (int mi = 0; mi < 4; ++mi)
            af[mi] = *reinterpret_cast<const bf16x8*>(&As[wr * 64 + mi * 16 + ql][g * 8]);
#pragma unroll
        for (int ni = 0; ni < 4; ++ni)
            bf[ni] = *reinterpret_cast<const bf16x8*>(&Bs[wc * 64 + ni * 16 + ql][g * 8]);
#pragma unroll
        for (int mi = 0; mi < 4; ++mi)
#pragma unroll
            for (int ni = 0; ni < 4; ++ni)
                acc[mi][ni] = __builtin_amdgcn_mfma_f32_16x16x32_bf16(af[mi], bf[ni], acc[mi][ni], 0, 0, 0);
    }

#pragma unroll
    for (int mi = 0; mi < 4; ++mi) {
        const int m0 = row0 + wr * 64 + mi * 16 + g * 4;
        const int b  = m0 >> 11, n0 = m0 & 2047;
#pragma unroll
        for (int ni = 0; ni < 4; ++ni) {
            const int c = col0 + wc * 64 + ni * 16 + ql;
            const int part = c >> 10, inner = c & 1023;
            const int h = inner >> 6, d = inner & 63;
            if (part == 2) {
                // permuted V store: col = [k5 k3 k2 k4 k1 k0] of key (n0&63).
                const int key0 = n0 & 63;
                const int nst  = (n0 & ~63)
                               | (key0 & 0x23)                 // k5, k1, k0
                               | (((key0 >> 3) & 1) << 4)      // k3 -> bit4
                               | (((key0 >> 2) & 1) << 3)      // k2 -> bit3
                               | (((key0 >> 4) & 1) << 2);     // k4 -> bit2
                u16x4 pk;
#pragma unroll
                for (int r = 0; r < 4; ++r) pk[r] = f2bf(acc[mi][ni][r]);
                *reinterpret_cast<u16x4*>(&vt[(((size_t)b * HEADS + h) * DHEAD + d) * NSEQ + nst]) = pk;
            } else if (part == 0) {
                unsigned short* dst = qb + (((size_t)b * HEADS + h) * NSEQ + n0) * DHEAD + d;
#pragma unroll
                for (int r = 0; r < 4; ++r) dst[(size_t)r * DHEAD] = f2bf(acc[mi][ni][r] * SC_L2E);
            } else {
                unsigned short* dst = kb + (((size_t)b * HEADS + h) * NSEQ + n0) * DHEAD + d;
#pragma unroll
                for (int r = 0; r < 4; ++r) dst[(size_t)r * DHEAD] = f2bf(acc[mi][ni][r]);
            }
        }
    }
}

// out-proj: N=1024, + bias, fp32 out
__global__ __launch_bounds__(256) void gemm_out_mfma(const unsigned short* __restrict__ A,
                                                     const unsigned short* __restrict__ Bt,
                                                     const float* __restrict__ bias,
                                                     float* __restrict__ out)
{
    __shared__ unsigned short As[128][32];
    __shared__ unsigned short Bs[128][32];

    const int t = threadIdx.x;
    const int l = t & 63, w = t >> 6;
    const int wr = w >> 1, wc = w & 1;
    const int g = l >> 4, ql = l & 15;
    const int row0 = blockIdx.y * 128;
    const int col0 = blockIdx.x * 128;
    const int lr = l >> 2, lc = l & 3;

    f32x4 acc[4][4];
#pragma unroll
    for (int mi = 0; mi < 4; ++mi)
#pragma unroll
        for (int ni = 0; ni < 4; ++ni)
#pragma unroll
            for (int r = 0; r < 4; ++r) acc[mi][ni][r] = 0.f;

    for (int k0 = 0; k0 < INNER; k0 += 32) {
        __syncthreads();
        {
            const unsigned short* ag = A  + (size_t)(row0 + 32 * w + lr) * INNER + k0 + lc * 8;
            const unsigned short* bg = Bt + (size_t)(col0 + 32 * w + lr) * INNER + k0 + lc * 8;
            GLDS16(ag,               &As[32 * w][0]);
            GLDS16(ag + 16 * INNER,  &As[32 * w + 16][0]);
            GLDS16(bg,               &Bs[32 * w][0]);
            GLDS16(bg + 16 * INNER,  &Bs[32 * w + 16][0]);
        }
        __syncthreads();

        bf16x8 af[4], bf[4];
#pragma unroll
        for (int mi = 0; mi < 4; ++mi)
            af[mi] = *reinterpret_cast<const bf16x8*>(&As[wr * 64 + mi * 16 + ql][g * 8]);
#pragma unroll
        for (int ni = 0; ni < 4; ++ni)
            bf[ni] = *reinterpret_cast<const bf16x8*>(&Bs[wc * 64 + ni * 16 + ql][g * 8]);
#pragma unroll
        for (int mi = 0; mi < 4; ++mi)
#pragma unroll
            for (int ni = 0; ni < 4; ++ni)
                acc[mi][ni] = __builtin_amdgcn_mfma_f32_16x16x32_bf16(af[mi], bf[ni], acc[mi][ni], 0, 0, 0);
    }

#pragma unroll
    for (int mi = 0; mi < 4; ++mi) {
        const int m0 = row0 + wr * 64 + mi * 16 + g * 4;
#pragma unroll
        for (int ni = 0; ni < 4; ++ni) {
            const int c = col0 + wc * 64 + ni * 16 + ql;
            const float bv = bias[c];
#pragma unroll
            for (int r = 0; r < 4; ++r)
                out[(size_t)(m0 + r) * DIM + c] = acc[mi][ni][r] + bv;
        }
    }
}

// ---------------------------------------------------------------------------
// MFMA flash attention, swapped operands: S^T = K·Q^T, O^T = V^T·P^T.
// 512 threads = 8 waves, Wq=16 (wave w owns q-rows w*16..+15), QBLK=128,
// grid (64,16). 4 blocks/CU x 8 waves = 32 waves/CU static occupancy.
// V columns pre-permuted in global so P stays in registers (no P LDS).
// K/V double-buffered XOR-swizzled LDS; single barrier per tile; defer-max.
// ---------------------------------------------------------------------------
__global__ __launch_bounds__(512) void attn_mfma(const unsigned short* __restrict__ qg,
                                                 const unsigned short* __restrict__ kg,
                                                 const unsigned short* __restrict__ vtg,
                                                 unsigned short* __restrict__ og)
{
    __shared__ unsigned short Ks [2][64 * 64];
    __shared__ unsigned short Vts[2][64 * 64];   // [d][j'] (permuted key cols)

    const int bh = blockIdx.x;
    const int b = bh >> 4, h = bh & 15;
    const int qblk = blockIdx.y;
    const int t = threadIdx.x, l = t & 63, w = t >> 6;    // w 0..7
    const int g = l >> 4, ql = l & 15;

    const size_t hb = (size_t)bh * NSEQ * DHEAD;

    // Q fragments (pre-scaled by SC_L2E); q-row = qblk*128 + w*16 + ql
    const unsigned short* qrow = qg + hb + (size_t)(qblk * 128 + w * 16 + ql) * DHEAD;
    const bf16x8 qf0 = *reinterpret_cast<const bf16x8*>(qrow + g * 8);
    const bf16x8 qf1 = *reinterpret_cast<const bf16x8*>(qrow + 32 + g * 8);

    // staging: 512 threads, one u16x8 (16B) per tensor each.
    // r = t>>3 (0..63), seg = t&7; swizzled slot (seg ^ (r&7)).
    const int r = t >> 3, seg = t & 7;
    const unsigned short* kgp = kg  + hb + (size_t)r * DHEAD + seg * 8;
    const unsigned short* vgp = vtg + hb + (size_t)r * NSEQ  + seg * 8;
    const int st = r * 64 + ((seg ^ (r & 7)) * 8);

    // prologue: stage tile 0 into buffer 0
    {
        u16x8 k0 = *reinterpret_cast<const u16x8*>(kgp);
        u16x8 v0 = *reinterpret_cast<const u16x8*>(vgp);
        *reinterpret_cast<u16x8*>(&Ks [0][st]) = k0;
        *reinterpret_cast<u16x8*>(&Vts[0][st]) = v0;
    }
    __syncthreads();

    // running prefetch pointers (strength-reduced)
    const unsigned short* kpre = kgp + 64 * DHEAD;
    const unsigned short* vpre = vgp + 64;

    f32x4 acc_o[4];
#pragma unroll
    for (int dt = 0; dt < 4; ++dt)
#pragma unroll
        for (int rr = 0; rr < 4; ++rr) acc_o[dt][rr] = 0.f;
    float m_r = -INFINITY, l_r = 0.f;

    for (int kbi = 0; kbi < NSEQ / 64; ++kbi) {
        const int cur = kbi & 1;
        // prefetch tile t+1 into registers
        u16x8 nk, nv;
        const bool pre = (kbi + 1 < NSEQ / 64);
        if (pre) {
            nk = *reinterpret_cast<const u16x8*>(kpre);
            nv = *reinterpret_cast<const u16x8*>(vpre);
            kpre += 64 * DHEAD;
            vpre += 64;
        }

        // S^T[j][q] = K[j][:]·Q[q][:]  (log2 domain, pre-scaled)
        f32x4 sacc[4];
#pragma unroll
        for (int jt = 0; jt < 4; ++jt)
#pragma unroll
            for (int rr = 0; rr < 4; ++rr) sacc[jt][rr] = 0.f;
        __builtin_amdgcn_s_setprio(1);
#pragma unroll
        for (int jt = 0; jt < 4; ++jt) {
            const int row = jt * 16 + ql;
            bf16x8 kf0 = *reinterpret_cast<const bf16x8*>(&Ks[cur][row * 64 + SWC(row, g * 8)]);
            bf16x8 kf1 = *reinterpret_cast<const bf16x8*>(&Ks[cur][row * 64 + SWC(row, 32 + g * 8)]);
            sacc[jt] = __builtin_amdgcn_mfma_f32_16x16x32_bf16(kf0, qf0, sacc[jt], 0, 0, 0);
            sacc[jt] = __builtin_amdgcn_mfma_f32_16x16x32_bf16(kf1, qf1, sacc[jt], 0, 0, 0);
        }
        __builtin_amdgcn_s_setprio(0);

        // online softmax with defer-max (per-lane q-column), on sacc directly
        float a0 = fmaxf(fmaxf(sacc[0][0], sacc[0][1]), sacc[0][2]);
        float a1 = fmaxf(fmaxf(sacc[0][3], sacc[1][0]), sacc[1][1]);
        float a2 = fmaxf(fmaxf(sacc[1][2], sacc[1][3]), sacc[2][0]);
        float a3 = fmaxf(fmaxf(sacc[2][1], sacc[2][2]), sacc[2][3]);
        float a4 = fmaxf(fmaxf(sacc[3][0], sacc[3][1]), sacc[3][2]);
        float mx = fmaxf(fmaxf(fmaxf(a0, a1), a2), fmaxf(fmaxf(a3, a4), sacc[3][3]));
        mx = fmaxf(mx, __shfl_xor(mx, 16));
        mx = fmaxf(mx, __shfl_xor(mx, 32));
        if (__any(mx > m_r + 8.f)) {
            const float m_new = fmaxf(m_r, mx);
            const float alpha = fexp2(m_r - m_new);
            l_r *= alpha;
#pragma unroll
            for (int dt = 0; dt < 4; ++dt)
#pragma unroll
                for (int rr = 0; rr < 4; ++rr) acc_o[dt][rr] *= alpha;
            m_r = m_new;
        }
        float p[16];
#pragma unroll
        for (int jt = 0; jt < 4; ++jt)
#pragma unroll
            for (int rr = 0; rr < 4; ++rr) p[jt * 4 + rr] = fexp2(sacc[jt][rr] - m_r);
        float s0 = (p[0] + p[1]) + (p[2] + p[3]);
        float s1 = (p[4] + p[5]) + (p[6] + p[7]);
        float s2 = (p[8] + p[9]) + (p[10] + p[11]);
        float s3 = (p[12] + p[13]) + (p[14] + p[15]);
        float ps = (s0 + s1) + (s2 + s3);
        ps += __shfl_xor(ps, 16);
        ps += __shfl_xor(ps, 32);
        l_r += ps;

        // pack P -> registers; V's global column permutation makes each
        // pf[js] the correct PV B-operand key order.
        bf16x8 pf[2];
#pragma unroll
        for (int js = 0; js < 2; ++js) {
            unsigned int u0 = cvtpk(p[8 * js + 0], p[8 * js + 1]);
            unsigned int u1 = cvtpk(p[8 * js + 2], p[8 * js + 3]);
            unsigned int u2 = cvtpk(p[8 * js + 4], p[8 * js + 5]);
            unsigned int u3 = cvtpk(p[8 * js + 6], p[8 * js + 7]);
            uint4 uu = {u0, u1, u2, u3};
            pf[js] = __builtin_bit_cast(bf16x8, uu);
        }

        // O^T[d][q] += Vt[d][:]·P^T[:][q]
        __builtin_amdgcn_s_setprio(1);
#pragma unroll
        for (int js = 0; js < 2; ++js)
#pragma unroll
            for (int dt = 0; dt < 4; ++dt) {
                const int row = dt * 16 + ql;
                bf16x8 vf = *reinterpret_cast<const bf16x8*>(&Vts[cur][row * 64 + SWC(row, js * 32 + g * 8)]);
                acc_o[dt] = __builtin_amdgcn_mfma_f32_16x16x32_bf16(vf, pf[js], acc_o[dt], 0, 0, 0);
            }
        __builtin_amdgcn_s_setprio(0);

        // stage tile t+1 into the alternate buffer
        if (pre) {
            *reinterpret_cast<u16x8*>(&Ks [cur ^ 1][st]) = nk;
            *reinterpret_cast<u16x8*>(&Vts[cur ^ 1][st]) = nv;
        }
        __syncthreads();
    }

    // epilogue: O[b][n][h*64+d], n = qblk*128 + w*16 + ql
    const float rinv = 1.0f / l_r;
    const int n = qblk * 128 + w * 16 + ql;
    unsigned short* dst = og + ((size_t)b * NSEQ + n) * INNER + h * DHEAD;
#pragma unroll
    for (int dt = 0; dt < 4; ++dt) {
        uint2 u;
        u.x = cvtpk(acc_o[dt][0] * rinv, acc_o[dt][1] * rinv);
        u.y = cvtpk(acc_o[dt][2] * rinv, acc_o[dt][3] * rinv);
        *reinterpret_cast<uint2*>(&dst[dt * 16 + g * 4]) = u;
    }
}

// ---------------------------------------------------------------------------

extern "C" void kernel_launch(void* const* d_in, const int* in_sizes, int n_in,
                              void* d_out, int out_size, void* d_ws, size_t ws_size,
                              hipStream_t stream) {
    const float* x     = (const float*)d_in[0];
    const float* w_qkv = (const float*)d_in[1];
    const float* w_out = (const float*)d_in[2];
    const float* b_out = (const float*)d_in[3];
    float* out = (float*)d_out;

    unsigned short* ws = (unsigned short*)d_ws;
    const size_t nX  = (size_t)MTOT * DIM;
    const size_t nWq = (size_t)DIM * 3 * INNER;
    const size_t nWo = (size_t)DIM * INNER;
    unsigned short* Xb  = ws;
    unsigned short* Wqt = Xb  + nX;
    unsigned short* Wot = Wqt + nWq;
    unsigned short* qb  = Wot + nWo;
    unsigned short* kb  = qb  + nX;
    unsigned short* vt  = kb  + nX;
    unsigned short* Ob  = vt  + nX;

    cvt_bf16<<<dim3(nX / 8 / 256), dim3(256), 0, stream>>>(x, Xb);
    transp_bf16<<<dim3(3 * INNER / 32, DIM / 32), dim3(256), 0, stream>>>(w_qkv, Wqt, DIM, 3 * INNER);
    transp_bf16<<<dim3(DIM / 32, INNER / 32), dim3(256), 0, stream>>>(w_out, Wot, INNER, DIM);

    gemm_qkv_mfma<<<dim3(3 * INNER / 128, MTOT / 128), dim3(256), 0, stream>>>(Xb, Wqt, qb, kb, vt);
    attn_mfma<<<dim3(BATCH * HEADS, NSEQ / 128), dim3(512), 0, stream>>>(qb, kb, vt, Ob);
    gemm_out_mfma<<<dim3(DIM / 128, MTOT / 128), dim3(256), 0, stream>>>(Ob, Wot, b_out, out);
}

// Round 9
// 202.357 us; speedup vs baseline: 22.0905x; 1.0451x over previous
//
#include <hip/hip_runtime.h>
#include <math.h>

#define BATCH   4
#define NSEQ    2048
#define DIM     1024
#define HEADS   16
#define DHEAD   64
#define INNER   1024
#define MTOT    (BATCH*NSEQ)     // 8192
// softmax in log2 domain: SCALE * log2(e), folded into Q at QKV epilogue
#define SC_L2E  0.04508422f

typedef __attribute__((ext_vector_type(8))) unsigned short u16x8;
typedef __attribute__((ext_vector_type(4))) unsigned short u16x4;
typedef __attribute__((ext_vector_type(8))) short          bf16x8;
typedef __attribute__((ext_vector_type(4))) float          f32x4;

__device__ __forceinline__ unsigned short f2bf(float f) {
    unsigned int u = __builtin_bit_cast(unsigned int, f);
    u += 0x7FFFu + ((u >> 16) & 1u);       // RNE
    return (unsigned short)(u >> 16);
}

__device__ __forceinline__ float fexp2(float x) {
    float r; asm("v_exp_f32 %0, %1" : "=v"(r) : "v"(x)); return r;
}

__device__ __forceinline__ unsigned int cvtpk(float lo, float hi) {
    unsigned int r; asm("v_cvt_pk_bf16_f32 %0, %1, %2" : "=v"(r) : "v"(lo), "v"(hi));
    return r;
}

// async global->LDS, 16B per lane; lds base must be wave-uniform
#define GLDS16(gp, lp) __builtin_amdgcn_global_load_lds( \
    (const __attribute__((address_space(1))) unsigned int*)(gp), \
    (__attribute__((address_space(3))) unsigned int*)(lp), 16, 0, 0)

// XOR swizzle: ushort column c (0..63) within row r -> permute 16B slots.
#define SWC(r, c) ((c) ^ (((r) & 7) << 3))

// ---------------------------------------------------------------------------
// fp32 -> bf16 elementwise convert (x)
// ---------------------------------------------------------------------------
__global__ __launch_bounds__(256) void cvt_bf16(const float* __restrict__ in,
                                                unsigned short* __restrict__ out)
{
    const int i = blockIdx.x * 256 + threadIdx.x;
    const float4* p = reinterpret_cast<const float4*>(in) + (size_t)i * 2;
    float4 a = p[0], b = p[1];
    u16x8 o;
    o[0]=f2bf(a.x); o[1]=f2bf(a.y); o[2]=f2bf(a.z); o[3]=f2bf(a.w);
    o[4]=f2bf(b.x); o[5]=f2bf(b.y); o[6]=f2bf(b.z); o[7]=f2bf(b.w);
    reinterpret_cast<u16x8*>(out)[i] = o;
}

// ---------------------------------------------------------------------------
// fp32 [R][C] -> bf16 [C][R] transpose (weights)
// ---------------------------------------------------------------------------
__global__ __launch_bounds__(256) void transp_bf16(const float* __restrict__ in,
                                                   unsigned short* __restrict__ out,
                                                   int R, int C)
{
    __shared__ float tile[32][33];
    const int c0 = blockIdx.x * 32, r0 = blockIdx.y * 32;
    const int tx = threadIdx.x & 31, ty = threadIdx.x >> 5;
#pragma unroll
    for (int i = 0; i < 32; i += 8)
        tile[ty + i][tx] = in[(size_t)(r0 + ty + i) * C + c0 + tx];
    __syncthreads();
#pragma unroll
    for (int i = 0; i < 32; i += 8)
        out[(size_t)(c0 + ty + i) * R + r0 + tx] = f2bf(tile[tx][ty + i]);
}

// ---------------------------------------------------------------------------
// bf16 MFMA GEMM, 128x128 tile, BK=32, 4 waves, global_load_lds staging.
// ---------------------------------------------------------------------------

// QKV: N=3072. Epilogue scatters q (pre-scaled by SC_L2E), k -> [b,h,n,d],
// v -> vt[b,h,d,n'] where n' permutes keys within each 64-block:
// key bits [k5 k4 k3 k2 k1 k0] -> col [k5 k3 k2 k4 k1 k0]. This makes the
// attn PV step consume P directly from each lane's S^T output registers.
__global__ __launch_bounds__(256) void gemm_qkv_mfma(const unsigned short* __restrict__ A,
                                                     const unsigned short* __restrict__ Bt,
                                                     unsigned short* __restrict__ qb,
                                                     unsigned short* __restrict__ kb,
                                                     unsigned short* __restrict__ vt)
{
    __shared__ unsigned short As[128][32];
    __shared__ unsigned short Bs[128][32];

    const int t = threadIdx.x;
    const int l = t & 63, w = t >> 6;
    const int wr = w >> 1, wc = w & 1;
    const int g = l >> 4, ql = l & 15;
    const int row0 = blockIdx.y * 128;
    const int col0 = blockIdx.x * 128;
    const int lr = l >> 2, lc = l & 3;     // staging lane mapping

    f32x4 acc[4][4];
#pragma unroll
    for (int mi = 0; mi < 4; ++mi)
#pragma unroll
        for (int ni = 0; ni < 4; ++ni)
#pragma unroll
            for (int r = 0; r < 4; ++r) acc[mi][ni][r] = 0.f;

    for (int k0 = 0; k0 < DIM; k0 += 32) {
        __syncthreads();
        {
            const unsigned short* ag = A  + (size_t)(row0 + 32 * w + lr) * DIM + k0 + lc * 8;
            const unsigned short* bg = Bt + (size_t)(col0 + 32 * w + lr) * DIM + k0 + lc * 8;
            GLDS16(ag,              &As[32 * w][0]);
            GLDS16(ag + 16 * DIM,   &As[32 * w + 16][0]);
            GLDS16(bg,              &Bs[32 * w][0]);
            GLDS16(bg + 16 * DIM,   &Bs[32 * w + 16][0]);
        }
        __syncthreads();

        bf16x8 af[4], bf[4];
#pragma unroll
        for (int mi = 0; mi < 4; ++mi)
            af[mi] = *reinterpret_cast<const bf16x8*>(&As[wr * 64 + mi * 16 + ql][g * 8]);
#pragma unroll
        for (int ni = 0; ni < 4; ++ni)
            bf[ni] = *reinterpret_cast<const bf16x8*>(&Bs[wc * 64 + ni * 16 + ql][g * 8]);
#pragma unroll
        for (int mi = 0; mi < 4; ++mi)
#pragma unroll
            for (int ni = 0; ni < 4; ++ni)
                acc[mi][ni] = __builtin_amdgcn_mfma_f32_16x16x32_bf16(af[mi], bf[ni], acc[mi][ni], 0, 0, 0);
    }

#pragma unroll
    for (int mi = 0; mi < 4; ++mi) {
        const int m0 = row0 + wr * 64 + mi * 16 + g * 4;
        const int b  = m0 >> 11, n0 = m0 & 2047;
#pragma unroll
        for (int ni = 0; ni < 4; ++ni) {
            const int c = col0 + wc * 64 + ni * 16 + ql;
            const int part = c >> 10, inner = c & 1023;
            const int h = inner >> 6, d = inner & 63;
            if (part == 2) {
                // permuted V store: col = [k5 k3 k2 k4 k1 k0] of key (n0&63).
                const int key0 = n0 & 63;
                const int nst  = (n0 & ~63)
                               | (key0 & 0x23)                 // k5, k1, k0
                               | (((key0 >> 3) & 1) << 4)      // k3 -> bit4
                               | (((key0 >> 2) & 1) << 3)      // k2 -> bit3
                               | (((key0 >> 4) & 1) << 2);     // k4 -> bit2
                u16x4 pk;
#pragma unroll
                for (int r = 0; r < 4; ++r) pk[r] = f2bf(acc[mi][ni][r]);
                *reinterpret_cast<u16x4*>(&vt[(((size_t)b * HEADS + h) * DHEAD + d) * NSEQ + nst]) = pk;
            } else if (part == 0) {
                unsigned short* dst = qb + (((size_t)b * HEADS + h) * NSEQ + n0) * DHEAD + d;
#pragma unroll
                for (int r = 0; r < 4; ++r) dst[(size_t)r * DHEAD] = f2bf(acc[mi][ni][r] * SC_L2E);
            } else {
                unsigned short* dst = kb + (((size_t)b * HEADS + h) * NSEQ + n0) * DHEAD + d;
#pragma unroll
                for (int r = 0; r < 4; ++r) dst[(size_t)r * DHEAD] = f2bf(acc[mi][ni][r]);
            }
        }
    }
}

// out-proj: N=1024, + bias, fp32 out
__global__ __launch_bounds__(256) void gemm_out_mfma(const unsigned short* __restrict__ A,
                                                     const unsigned short* __restrict__ Bt,
                                                     const float* __restrict__ bias,
                                                     float* __restrict__ out)
{
    __shared__ unsigned short As[128][32];
    __shared__ unsigned short Bs[128][32];

    const int t = threadIdx.x;
    const int l = t & 63, w = t >> 6;
    const int wr = w >> 1, wc = w & 1;
    const int g = l >> 4, ql = l & 15;
    const int row0 = blockIdx.y * 128;
    const int col0 = blockIdx.x * 128;
    const int lr = l >> 2, lc = l & 3;

    f32x4 acc[4][4];
#pragma unroll
    for (int mi = 0; mi < 4; ++mi)
#pragma unroll
        for (int ni = 0; ni < 4; ++ni)
#pragma unroll
            for (int r = 0; r < 4; ++r) acc[mi][ni][r] = 0.f;

    for (int k0 = 0; k0 < INNER; k0 += 32) {
        __syncthreads();
        {
            const unsigned short* ag = A  + (size_t)(row0 + 32 * w + lr) * INNER + k0 + lc * 8;
            const unsigned short* bg = Bt + (size_t)(col0 + 32 * w + lr) * INNER + k0 + lc * 8;
            GLDS16(ag,               &As[32 * w][0]);
            GLDS16(ag + 16 * INNER,  &As[32 * w + 16][0]);
            GLDS16(bg,               &Bs[32 * w][0]);
            GLDS16(bg + 16 * INNER,  &Bs[32 * w + 16][0]);
        }
        __syncthreads();

        bf16x8 af[4], bf[4];
#pragma unroll
        for (int mi = 0; mi < 4; ++mi)
            af[mi] = *reinterpret_cast<const bf16x8*>(&As[wr * 64 + mi * 16 + ql][g * 8]);
#pragma unroll
        for (int ni = 0; ni < 4; ++ni)
            bf[ni] = *reinterpret_cast<const bf16x8*>(&Bs[wc * 64 + ni * 16 + ql][g * 8]);
#pragma unroll
        for (int mi = 0; mi < 4; ++mi)
#pragma unroll
            for (int ni = 0; ni < 4; ++ni)
                acc[mi][ni] = __builtin_amdgcn_mfma_f32_16x16x32_bf16(af[mi], bf[ni], acc[mi][ni], 0, 0, 0);
    }

#pragma unroll
    for (int mi = 0; mi < 4; ++mi) {
        const int m0 = row0 + wr * 64 + mi * 16 + g * 4;
#pragma unroll
        for (int ni = 0; ni < 4; ++ni) {
            const int c = col0 + wc * 64 + ni * 16 + ql;
            const float bv = bias[c];
#pragma unroll
            for (int r = 0; r < 4; ++r)
                out[(size_t)(m0 + r) * DIM + c] = acc[mi][ni][r] + bv;
        }
    }
}

// ---------------------------------------------------------------------------
// MFMA flash attention, swapped operands: S^T = K·Q^T, O^T = V^T·P^T.
// 512 threads = 8 waves, Wq=32 (wave w owns q-rows w*32..+31, two halves),
// QBLK=256, grid (64,8) = 512 blocks = exactly 2/CU, 16 waves/CU.
// K/V fragments read once per wave-tile serve 32 q-rows (half the LDS
// traffic of Wq=16). V columns pre-permuted in global so P stays in
// registers (no P LDS). Double-buffered swizzled K/V; 1 barrier/tile.
// ---------------------------------------------------------------------------
__global__ __launch_bounds__(512) void attn_mfma(const unsigned short* __restrict__ qg,
                                                 const unsigned short* __restrict__ kg,
                                                 const unsigned short* __restrict__ vtg,
                                                 unsigned short* __restrict__ og)
{
    __shared__ unsigned short Ks [2][64 * 64];
    __shared__ unsigned short Vts[2][64 * 64];   // [d][j'] (permuted key cols)

    const int bh = blockIdx.x;
    const int b = bh >> 4, h = bh & 15;
    const int qblk = blockIdx.y;
    const int t = threadIdx.x, l = t & 63, w = t >> 6;    // w 0..7
    const int g = l >> 4, ql = l & 15;

    const size_t hb = (size_t)bh * NSEQ * DHEAD;

    // Q fragments for both q-halves (pre-scaled by SC_L2E)
    bf16x8 qf[2][2];
#pragma unroll
    for (int qh = 0; qh < 2; ++qh) {
        const unsigned short* qrow = qg + hb + (size_t)(qblk * 256 + w * 32 + qh * 16 + ql) * DHEAD;
        qf[qh][0] = *reinterpret_cast<const bf16x8*>(qrow + g * 8);
        qf[qh][1] = *reinterpret_cast<const bf16x8*>(qrow + 32 + g * 8);
    }

    // staging: 512 threads, one u16x8 (16B) per tensor each.
    // r = t>>3 (0..63), seg = t&7; swizzled slot (seg ^ (r&7)).
    const int r = t >> 3, seg = t & 7;
    const unsigned short* kgp = kg  + hb + (size_t)r * DHEAD + seg * 8;
    const unsigned short* vgp = vtg + hb + (size_t)r * NSEQ  + seg * 8;
    const int st = r * 64 + ((seg ^ (r & 7)) * 8);

    // prologue: stage tile 0 into buffer 0
    {
        u16x8 k0 = *reinterpret_cast<const u16x8*>(kgp);
        u16x8 v0 = *reinterpret_cast<const u16x8*>(vgp);
        *reinterpret_cast<u16x8*>(&Ks [0][st]) = k0;
        *reinterpret_cast<u16x8*>(&Vts[0][st]) = v0;
    }
    __syncthreads();

    // running prefetch pointers (strength-reduced)
    const unsigned short* kpre = kgp + 64 * DHEAD;
    const unsigned short* vpre = vgp + 64;

    f32x4 acc_o[2][4];
#pragma unroll
    for (int qh = 0; qh < 2; ++qh)
#pragma unroll
        for (int dt = 0; dt < 4; ++dt)
#pragma unroll
            for (int rr = 0; rr < 4; ++rr) acc_o[qh][dt][rr] = 0.f;
    float m_r[2] = {-INFINITY, -INFINITY};
    float l_r[2] = {0.f, 0.f};

    for (int kbi = 0; kbi < NSEQ / 64; ++kbi) {
        const int cur = kbi & 1;
        // prefetch tile t+1 into registers
        u16x8 nk, nv;
        const bool pre = (kbi + 1 < NSEQ / 64);
        if (pre) {
            nk = *reinterpret_cast<const u16x8*>(kpre);
            nv = *reinterpret_cast<const u16x8*>(vpre);
            kpre += 64 * DHEAD;
            vpre += 64;
        }

        // S^T[j][q] = K[j][:]·Q[q][:] for both q-halves; kf read once per jt
        f32x4 sacc[2][4];
#pragma unroll
        for (int qh = 0; qh < 2; ++qh)
#pragma unroll
            for (int jt = 0; jt < 4; ++jt)
#pragma unroll
                for (int rr = 0; rr < 4; ++rr) sacc[qh][jt][rr] = 0.f;
        __builtin_amdgcn_s_setprio(1);
#pragma unroll
        for (int jt = 0; jt < 4; ++jt) {
            const int row = jt * 16 + ql;
            bf16x8 kf0 = *reinterpret_cast<const bf16x8*>(&Ks[cur][row * 64 + SWC(row, g * 8)]);
            bf16x8 kf1 = *reinterpret_cast<const bf16x8*>(&Ks[cur][row * 64 + SWC(row, 32 + g * 8)]);
            sacc[0][jt] = __builtin_amdgcn_mfma_f32_16x16x32_bf16(kf0, qf[0][0], sacc[0][jt], 0, 0, 0);
            sacc[0][jt] = __builtin_amdgcn_mfma_f32_16x16x32_bf16(kf1, qf[0][1], sacc[0][jt], 0, 0, 0);
            sacc[1][jt] = __builtin_amdgcn_mfma_f32_16x16x32_bf16(kf0, qf[1][0], sacc[1][jt], 0, 0, 0);
            sacc[1][jt] = __builtin_amdgcn_mfma_f32_16x16x32_bf16(kf1, qf[1][1], sacc[1][jt], 0, 0, 0);
        }
        __builtin_amdgcn_s_setprio(0);

        // per-half online softmax with defer-max; pack P into registers
        bf16x8 pf[2][2];
#pragma unroll
        for (int qh = 0; qh < 2; ++qh) {
            float a0 = fmaxf(fmaxf(sacc[qh][0][0], sacc[qh][0][1]), sacc[qh][0][2]);
            float a1 = fmaxf(fmaxf(sacc[qh][0][3], sacc[qh][1][0]), sacc[qh][1][1]);
            float a2 = fmaxf(fmaxf(sacc[qh][1][2], sacc[qh][1][3]), sacc[qh][2][0]);
            float a3 = fmaxf(fmaxf(sacc[qh][2][1], sacc[qh][2][2]), sacc[qh][2][3]);
            float a4 = fmaxf(fmaxf(sacc[qh][3][0], sacc[qh][3][1]), sacc[qh][3][2]);
            float mx = fmaxf(fmaxf(fmaxf(a0, a1), a2), fmaxf(fmaxf(a3, a4), sacc[qh][3][3]));
            mx = fmaxf(mx, __shfl_xor(mx, 16));
            mx = fmaxf(mx, __shfl_xor(mx, 32));
            if (__any(mx > m_r[qh] + 8.f)) {
                const float m_new = fmaxf(m_r[qh], mx);
                const float alpha = fexp2(m_r[qh] - m_new);
                l_r[qh] *= alpha;
#pragma unroll
                for (int dt = 0; dt < 4; ++dt)
#pragma unroll
                    for (int rr = 0; rr < 4; ++rr) acc_o[qh][dt][rr] *= alpha;
                m_r[qh] = m_new;
            }
            float p[16];
#pragma unroll
            for (int jt = 0; jt < 4; ++jt)
#pragma unroll
                for (int rr = 0; rr < 4; ++rr)
                    p[jt * 4 + rr] = fexp2(sacc[qh][jt][rr] - m_r[qh]);
            float s0 = (p[0] + p[1]) + (p[2] + p[3]);
            float s1 = (p[4] + p[5]) + (p[6] + p[7]);
            float s2 = (p[8] + p[9]) + (p[10] + p[11]);
            float s3 = (p[12] + p[13]) + (p[14] + p[15]);
            float ps = (s0 + s1) + (s2 + s3);
            ps += __shfl_xor(ps, 16);
            ps += __shfl_xor(ps, 32);
            l_r[qh] += ps;

            // pack: pf[qh][js] covers p[8*js..8*js+7]; V's global column
            // permutation makes this the correct key order for PV.
#pragma unroll
            for (int js = 0; js < 2; ++js) {
                unsigned int u0 = cvtpk(p[8 * js + 0], p[8 * js + 1]);
                unsigned int u1 = cvtpk(p[8 * js + 2], p[8 * js + 3]);
                unsigned int u2 = cvtpk(p[8 * js + 4], p[8 * js + 5]);
                unsigned int u3 = cvtpk(p[8 * js + 6], p[8 * js + 7]);
                uint4 uu = {u0, u1, u2, u3};
                pf[qh][js] = __builtin_bit_cast(bf16x8, uu);
            }
        }

        // O^T[d][q] += Vt[d][:]·P^T[:][q]; vf read once per (js,dt), used 2x
        __builtin_amdgcn_s_setprio(1);
#pragma unroll
        for (int js = 0; js < 2; ++js) {
            bf16x8 vf[4];
#pragma unroll
            for (int dt = 0; dt < 4; ++dt) {
                const int row = dt * 16 + ql;
                vf[dt] = *reinterpret_cast<const bf16x8*>(&Vts[cur][row * 64 + SWC(row, js * 32 + g * 8)]);
            }
#pragma unroll
            for (int qh = 0; qh < 2; ++qh)
#pragma unroll
                for (int dt = 0; dt < 4; ++dt)
                    acc_o[qh][dt] = __builtin_amdgcn_mfma_f32_16x16x32_bf16(vf[dt], pf[qh][js], acc_o[qh][dt], 0, 0, 0);
        }
        __builtin_amdgcn_s_setprio(0);

        // stage tile t+1 into the alternate buffer
        if (pre) {
            *reinterpret_cast<u16x8*>(&Ks [cur ^ 1][st]) = nk;
            *reinterpret_cast<u16x8*>(&Vts[cur ^ 1][st]) = nv;
        }
        __syncthreads();
    }

    // epilogue: O[b][n][h*64+d], n = qblk*256 + w*32 + qh*16 + ql
#pragma unroll
    for (int qh = 0; qh < 2; ++qh) {
        const float rinv = 1.0f / l_r[qh];
        const int n = qblk * 256 + w * 32 + qh * 16 + ql;
        unsigned short* dst = og + ((size_t)b * NSEQ + n) * INNER + h * DHEAD;
#pragma unroll
        for (int dt = 0; dt < 4; ++dt) {
            uint2 u;
            u.x = cvtpk(acc_o[qh][dt][0] * rinv, acc_o[qh][dt][1] * rinv);
            u.y = cvtpk(acc_o[qh][dt][2] * rinv, acc_o[qh][dt][3] * rinv);
            *reinterpret_cast<uint2*>(&dst[dt * 16 + g * 4]) = u;
        }
    }
}

// ---------------------------------------------------------------------------

extern "C" void kernel_launch(void* const* d_in, const int* in_sizes, int n_in,
                              void* d_out, int out_size, void* d_ws, size_t ws_size,
                              hipStream_t stream) {
    const float* x     = (const float*)d_in[0];
    const float* w_qkv = (const float*)d_in[1];
    const float* w_out = (const float*)d_in[2];
    const float* b_out = (const float*)d_in[3];
    float* out = (float*)d_out;

    unsigned short* ws = (unsigned short*)d_ws;
    const size_t nX  = (size_t)MTOT * DIM;
    const size_t nWq = (size_t)DIM * 3 * INNER;
    const size_t nWo = (size_t)DIM * INNER;
    unsigned short* Xb  = ws;
    unsigned short* Wqt = Xb  + nX;
    unsigned short* Wot = Wqt + nWq;
    unsigned short* qb  = Wot + nWo;
    unsigned short* kb  = qb  + nX;
    unsigned short* vt  = kb  + nX;
    unsigned short* Ob  = vt  + nX;

    cvt_bf16<<<dim3(nX / 8 / 256), dim3(256), 0, stream>>>(x, Xb);
    transp_bf16<<<dim3(3 * INNER / 32, DIM / 32), dim3(256), 0, stream>>>(w_qkv, Wqt, DIM, 3 * INNER);
    transp_bf16<<<dim3(DIM / 32, INNER / 32), dim3(256), 0, stream>>>(w_out, Wot, INNER, DIM);

    gemm_qkv_mfma<<<dim3(3 * INNER / 128, MTOT / 128), dim3(256), 0, stream>>>(Xb, Wqt, qb, kb, vt);
    attn_mfma<<<dim3(BATCH * HEADS, NSEQ / 256), dim3(512), 0, stream>>>(qb, kb, vt, Ob);
    gemm_out_mfma<<<dim3(DIM / 128, MTOT / 128), dim3(256), 0, stream>>>(Ob, Wot, b_out, out);
}